// Round 1
// baseline (863.658 us; speedup 1.0000x reference)
//
#include <hip/hip_runtime.h>
#include <math.h>

#define NN 5000
#define NBINS 50
#define BINSZ 100
#define KNN 16
#define NEDGE 80000   // NBINS*BINSZ*KNN

__device__ __forceinline__ float lrelu(float x){ return x >= 0.f ? x : 0.01f*x; }

// out[n*J+j] = act(b[j] + sum_k in[n*Kd+k] * W[k*J+j]);  W row-major [Kd,J]
__global__ void lin_kernel(const float* __restrict__ in, const float* __restrict__ W,
                           const float* __restrict__ b, float* __restrict__ out,
                           int N, int Kd, int J, int act) {
    int t = blockIdx.x * blockDim.x + threadIdx.x;
    if (t >= N * J) return;
    int n = t / J, j = t - n * J;
    float acc = b[j];
    const float* inp = in + n * Kd;
    for (int k = 0; k < Kd; ++k) acc += inp[k] * W[k * J + j];
    if (act) acc = lrelu(acc);
    out[t] = acc;
}

// no-bias linear: out[n*J+j] = sum_k in[n*Kd+k] * W[k*J+j]
__global__ void lin_nb_kernel(const float* __restrict__ in, const float* __restrict__ W,
                              float* __restrict__ out, int N, int Kd, int J) {
    int t = blockIdx.x * blockDim.x + threadIdx.x;
    if (t >= N * J) return;
    int n = t / J, j = t - n * J;
    float acc = 0.f;
    const float* inp = in + n * Kd;
    for (int k = 0; k < Kd; ++k) acc += inp[k] * W[k * J + j];
    out[t] = acc;
}

// bin_idx[i] = argmax over [mul[0..24], -mul[0..24]]  (first max wins, like jnp.argmax)
__global__ void bin_kernel(const float* __restrict__ h, const float* __restrict__ cb,
                           int* __restrict__ bin_idx) {
    int i = blockIdx.x * blockDim.x + threadIdx.x;
    if (i >= NN) return;
    float hv[12];
    for (int k = 0; k < 12; ++k) hv[k] = h[i * 12 + k];
    float mul[25];
    for (int c = 0; c < 25; ++c) {
        float m = 0.f;
        for (int k = 0; k < 12; ++k) m += hv[k] * cb[k * 100 + c];  // codebook is [12,100]
        mul[c] = m;
    }
    float best = -INFINITY; int bi = 0;
    for (int c = 0; c < 50; ++c) {
        float v = (c < 25) ? mul[c] : -mul[c - 25];
        if (v > best) { best = v; bi = c; }
    }
    bin_idx[i] = bi;
}

// stable counting sort by bin_idx: order[] = argsort(bin_idx, stable)
__global__ void order_kernel(const int* __restrict__ bin_idx, int* __restrict__ order) {
    __shared__ int counts[NBINS];
    __shared__ int offs[NBINS];
    int b = threadIdx.x;
    if (b < NBINS) {
        int c = 0;
        for (int i = 0; i < NN; ++i) if (bin_idx[i] == b) c++;
        counts[b] = c;
    }
    __syncthreads();
    if (threadIdx.x == 0) {
        int s = 0;
        for (int q = 0; q < NBINS; ++q) { offs[q] = s; s += counts[q]; }
    }
    __syncthreads();
    if (b < NBINS) {
        int p = offs[b];
        for (int i = 0; i < NN; ++i) if (bin_idx[i] == b) order[p++] = i;
    }
}

// per chunk p (50 blocks): gram matrix + sigmoid + top-16 per row -> edges
__global__ void knn_kernel(const float* __restrict__ h, const int* __restrict__ order,
                           int* __restrict__ src, int* __restrict__ dst,
                           float* __restrict__ ew) {
    int p = blockIdx.x;
    __shared__ float pts[BINSZ * 12];
    __shared__ int nodes[BINSZ];
    for (int t = threadIdx.x; t < BINSZ; t += blockDim.x) {
        int node = order[p * BINSZ + t];
        nodes[t] = node;
        for (int k = 0; k < 12; ++k) pts[t * 12 + k] = h[node * 12 + k];
    }
    __syncthreads();
    int i = threadIdx.x;
    if (i < BINSZ) {
        float xi[12];
        for (int k = 0; k < 12; ++k) xi[k] = pts[i * 12 + k];
        float tv[KNN]; int ti[KNN];
        for (int k = 0; k < KNN; ++k) { tv[k] = -1e30f; ti[k] = 0; }
        for (int j = 0; j < BINSZ; ++j) {
            float d = 0.f;
            for (int k = 0; k < 12; ++k) d += xi[k] * pts[j * 12 + k];
            float v = 1.f / (1.f + expf(-d));
            if (v > tv[KNN - 1]) {
                int pos = KNN - 1;
                while (pos > 0 && v > tv[pos - 1]) {
                    tv[pos] = tv[pos - 1]; ti[pos] = ti[pos - 1]; pos--;
                }
                tv[pos] = v; ti[pos] = j;
            }
        }
        int base = (p * BINSZ + i) * KNN;
        int me = nodes[i];
        for (int k = 0; k < KNN; ++k) {
            src[base + k] = me;
            dst[base + k] = nodes[ti[k]];
            ew[base + k]  = tv[k];
        }
    }
}

__global__ void leaky_kernel(const float* __restrict__ in, float* __restrict__ out, int n) {
    int t = blockIdx.x * blockDim.x + threadIdx.x;
    if (t < n) out[t] = lrelu(in[t]);
}

__global__ void deg_init_kernel(float* __restrict__ deg) {
    int t = blockIdx.x * blockDim.x + threadIdx.x;
    if (t < NN) deg[t] = 1.0f;   // self-loop weight
}

__global__ void deg_edge_kernel(const int* __restrict__ dst, const float* __restrict__ ew,
                                float* __restrict__ deg) {
    int e = blockIdx.x * blockDim.x + threadIdx.x;
    if (e < NEDGE) atomicAdd(&deg[dst[e]], ew[e]);
}

__global__ void dis_kernel(const float* __restrict__ deg, float* __restrict__ dis) {
    int t = blockIdx.x * blockDim.x + threadIdx.x;
    if (t < NN) {
        float d = deg[t];
        dis[t] = d > 0.f ? 1.0f / sqrtf(d) : 0.0f;
    }
}

// self-loop term + bias: out[n][c] = dis[n]^2 * hW[n][c] + b[c]
__global__ void gcn_init_kernel(const float* __restrict__ dis, const float* __restrict__ hW,
                                const float* __restrict__ b, float* __restrict__ out) {
    int t = blockIdx.x * blockDim.x + threadIdx.x;
    if (t >= NN * 32) return;
    int n = t >> 5, c = t & 31;
    float d = dis[n];
    out[t] = d * d * hW[t] + b[c];
}

__global__ void gcn_edge_kernel(const int* __restrict__ src, const int* __restrict__ dst,
                                const float* __restrict__ ew, const float* __restrict__ dis,
                                const float* __restrict__ hW, float* __restrict__ out) {
    int t = blockIdx.x * blockDim.x + threadIdx.x;
    if (t >= NEDGE * 32) return;
    int e = t >> 5, c = t & 31;
    int s = src[e], d = dst[e];
    float coef = dis[s] * ew[e] * dis[d];
    atomicAdd(&out[d * 32 + c], coef * hW[s * 32 + c]);
}

__global__ void agg_edge_kernel(const int* __restrict__ src, const int* __restrict__ dst,
                                const float* __restrict__ ew, const float* __restrict__ x,
                                float* __restrict__ agg) {
    int t = blockIdx.x * blockDim.x + threadIdx.x;
    if (t >= NEDGE * 32) return;
    int e = t >> 5, c = t & 31;
    atomicAdd(&agg[dst[e] * 32 + c], ew[e] * x[src[e] * 32 + c]);
}

// out = leaky(agg @ Wrel + brel + x @ Wroot)
__global__ void gc_combine_kernel(const float* __restrict__ agg, const float* __restrict__ x,
                                  const float* __restrict__ Wrel, const float* __restrict__ brel,
                                  const float* __restrict__ Wroot, float* __restrict__ out) {
    int t = blockIdx.x * blockDim.x + threadIdx.x;
    if (t >= NN * 32) return;
    int n = t >> 5, j = t & 31;
    float acc = brel[j];
    for (int k = 0; k < 32; ++k)
        acc += agg[n * 32 + k] * Wrel[k * 32 + j] + x[n * 32 + k] * Wroot[k * 32 + j];
    out[t] = lrelu(acc);
}

__global__ void concat_kernel(const float* __restrict__ a, const float* __restrict__ b,
                              float* __restrict__ out) {
    int t = blockIdx.x * blockDim.x + threadIdx.x;
    if (t >= NN * 38) return;
    int n = t / 38, j = t - n * 38;
    out[t] = (j < 32) ? a[n * 32 + j] : b[n * 6 + (j - 32)];
}

static inline int cdiv(int a, int b) { return (a + b - 1) / b; }

extern "C" void kernel_launch(void* const* d_in, const int* in_sizes, int n_in,
                              void* d_out, int out_size, void* d_ws, size_t ws_size,
                              hipStream_t stream) {
    const float* x        = (const float*)d_in[0];
    const float* ygen_id  = (const float*)d_in[1];
    const float* ygen     = (const float*)d_in[2];
    const float* codebook = (const float*)d_in[3];
    const float* nn1_W1 = (const float*)d_in[4];  const float* nn1_b1 = (const float*)d_in[5];
    const float* nn1_W2 = (const float*)d_in[6];  const float* nn1_b2 = (const float*)d_in[7];
    const float* nn1_W3 = (const float*)d_in[8];  const float* nn1_b3 = (const float*)d_in[9];
    const float* gcn_W  = (const float*)d_in[10]; const float* gcn_b  = (const float*)d_in[11];
    const float* gc_Wrel = (const float*)d_in[12]; const float* gc_brel = (const float*)d_in[13];
    const float* gc_Wroot = (const float*)d_in[14];
    const float* nn2_W1 = (const float*)d_in[15]; const float* nn2_b1 = (const float*)d_in[16];
    const float* nn2_W2 = (const float*)d_in[17]; const float* nn2_b2 = (const float*)d_in[18];
    const float* nn2_W3 = (const float*)d_in[19]; const float* nn2_b3 = (const float*)d_in[20];
    const float* nn3_W1 = (const float*)d_in[21]; const float* nn3_b1 = (const float*)d_in[22];
    const float* nn3_W2 = (const float*)d_in[23]; const float* nn3_b2 = (const float*)d_in[24];
    const float* nn3_W3 = (const float*)d_in[25]; const float* nn3_b3 = (const float*)d_in[26];

    float* out = (float*)d_out;
    float* ws  = (float*)d_ws;

    // workspace layout (float offsets)
    float* hbuf1   = ws + 0;        // 625000  (5000x125)
    float* hbuf2   = ws + 625000;   // 625000
    float* h       = ws + 1250000;  // 60000   (5000x12) pre-leaky
    float* h_lr    = ws + 1310000;  // 60000
    float* hW      = ws + 1370000;  // 160000  (5000x32, no bias)
    float* gcn_out = ws + 1530000;  // 160000
    float* agg     = ws + 1690000;  // 160000
    float* gc_out  = ws + 1850000;  // 160000
    float* cat     = ws + 2010000;  // 190000  (5000x38)
    float* deg     = ws + 2200000;  // 5000
    float* dis     = ws + 2205000;  // 5000
    float* ew      = ws + 2210000;  // 80000
    int*   bin_idx = (int*)(ws + 2290000);  // 5000
    int*   order   = (int*)(ws + 2295000);  // 5000
    int*   src     = (int*)(ws + 2300000);  // 80000
    int*   dst     = (int*)(ws + 2380000);  // 80000

    const int T = 256;

    // nn1: 12 -> 125 -> 125 -> 12
    lin_kernel<<<cdiv(NN*125, T), T, 0, stream>>>(x, nn1_W1, nn1_b1, hbuf1, NN, 12, 125, 1);
    lin_kernel<<<cdiv(NN*125, T), T, 0, stream>>>(hbuf1, nn1_W2, nn1_b2, hbuf2, NN, 125, 125, 1);
    lin_kernel<<<cdiv(NN*12, T), T, 0, stream>>>(hbuf2, nn1_W3, nn1_b3, h, NN, 125, 12, 0);

    // graph building on pre-leaky h
    bin_kernel<<<cdiv(NN, T), T, 0, stream>>>(h, codebook, bin_idx);
    order_kernel<<<1, 64, 0, stream>>>(bin_idx, order);
    knn_kernel<<<NBINS, 128, 0, stream>>>(h, order, src, dst, ew);

    // leaky on h
    leaky_kernel<<<cdiv(NN*12, T), T, 0, stream>>>(h, h_lr, NN*12);

    // GCNConv
    deg_init_kernel<<<cdiv(NN, T), T, 0, stream>>>(deg);
    deg_edge_kernel<<<cdiv(NEDGE, T), T, 0, stream>>>(dst, ew, deg);
    dis_kernel<<<cdiv(NN, T), T, 0, stream>>>(deg, dis);
    lin_nb_kernel<<<cdiv(NN*32, T), T, 0, stream>>>(h_lr, gcn_W, hW, NN, 12, 32);
    gcn_init_kernel<<<cdiv(NN*32, T), T, 0, stream>>>(dis, hW, gcn_b, gcn_out);
    gcn_edge_kernel<<<cdiv(NEDGE*32, T), T, 0, stream>>>(src, dst, ew, dis, hW, gcn_out);

    // GraphConv
    hipMemsetAsync(agg, 0, NN * 32 * sizeof(float), stream);
    agg_edge_kernel<<<cdiv(NEDGE*32, T), T, 0, stream>>>(src, dst, ew, gcn_out, agg);
    gc_combine_kernel<<<cdiv(NN*32, T), T, 0, stream>>>(agg, gcn_out, gc_Wrel, gc_brel, gc_Wroot, gc_out);

    // nn2: 32 -> 125 -> 125 -> 6  (cand_ids -> out[0:30000])
    lin_kernel<<<cdiv(NN*125, T), T, 0, stream>>>(gc_out, nn2_W1, nn2_b1, hbuf1, NN, 32, 125, 1);
    lin_kernel<<<cdiv(NN*125, T), T, 0, stream>>>(hbuf1, nn2_W2, nn2_b2, hbuf2, NN, 125, 125, 1);
    lin_kernel<<<cdiv(NN*6, T), T, 0, stream>>>(hbuf2, nn2_W3, nn2_b3, out, NN, 125, 6, 0);

    // nn3: concat(gc_out, cand_ids) 38 -> 125 -> 125 -> 6 (cand_p4 -> out[30000:60000])
    concat_kernel<<<cdiv(NN*38, T), T, 0, stream>>>(gc_out, out, cat);
    lin_kernel<<<cdiv(NN*125, T), T, 0, stream>>>(cat, nn3_W1, nn3_b1, hbuf1, NN, 38, 125, 1);
    lin_kernel<<<cdiv(NN*125, T), T, 0, stream>>>(hbuf1, nn3_W2, nn3_b2, hbuf2, NN, 125, 125, 1);
    lin_kernel<<<cdiv(NN*6, T), T, 0, stream>>>(hbuf2, nn3_W3, nn3_b3, out + 30000, NN, 125, 6, 0);

    // passthrough outputs
    hipMemcpyAsync(out + 60000, ygen_id, 30000 * sizeof(float), hipMemcpyDeviceToDevice, stream);
    hipMemcpyAsync(out + 90000, ygen, 30000 * sizeof(float), hipMemcpyDeviceToDevice, stream);
}

// Round 2
// 650.916 us; speedup vs baseline: 1.3268x; 1.3268x over previous
//
#include <hip/hip_runtime.h>
#include <math.h>

#define NN 5000
#define NBINS 50
#define BINSZ 100
#define KNN 16
#define NEDGE 80000   // NBINS*BINSZ*KNN

__device__ __forceinline__ float lrelu(float x){ return x >= 0.f ? x : 0.01f*x; }

// ---------------- fused MLP 1: x[5000,12] -> 125 -> 125 -> 12 (h, pre-leaky) --------
#define MNODES 16
__global__ __launch_bounds__(128) void nn1_kernel(
    const float* __restrict__ x,
    const float* __restrict__ W1, const float* __restrict__ b1,
    const float* __restrict__ W2, const float* __restrict__ b2,
    const float* __restrict__ W3, const float* __restrict__ b3,
    float* __restrict__ h_out) {
    __shared__ float s_in[MNODES * 12];
    __shared__ float s_h1[MNODES * 125];
    __shared__ float s_h2[MNODES * 125];
    int tid = threadIdx.x;
    int n0 = blockIdx.x * MNODES;
    int nmax = NN - n0; if (nmax > MNODES) nmax = MNODES;

    for (int t = tid; t < nmax * 12; t += 128) s_in[t] = x[n0 * 12 + t];
    __syncthreads();
    // L1: 12 -> 125, leaky
    for (int o = tid; o < nmax * 125; o += 128) {
        int n = o / 125, j = o - n * 125;
        float acc = b1[j];
        for (int k = 0; k < 12; ++k) acc += s_in[n * 12 + k] * W1[k * 125 + j];
        s_h1[o] = lrelu(acc);
    }
    __syncthreads();
    // L2: 125 -> 125, leaky
    for (int o = tid; o < nmax * 125; o += 128) {
        int n = o / 125, j = o - n * 125;
        float acc = b2[j];
        for (int k = 0; k < 125; ++k) acc += s_h1[n * 125 + k] * W2[k * 125 + j];
        s_h2[o] = lrelu(acc);
    }
    __syncthreads();
    // L3: 125 -> 12, no act
    for (int o = tid; o < nmax * 12; o += 128) {
        int n = o / 12, j = o - n * 12;
        float acc = b3[j];
        for (int k = 0; k < 125; ++k) acc += s_h2[n * 125 + k] * W3[k * 12 + j];
        h_out[n0 * 12 + o] = acc;
    }
}

// ---------------- bin assignment + per-bin counts (counts must be pre-zeroed) -------
__global__ __launch_bounds__(256) void bin_kernel(
    const float* __restrict__ h, const float* __restrict__ cb,
    int* __restrict__ bin_idx, int* __restrict__ counts) {
    int i = blockIdx.x * blockDim.x + threadIdx.x;
    if (i >= NN) return;
    float hv[12];
    for (int k = 0; k < 12; ++k) hv[k] = h[i * 12 + k];
    float mul[25];
    for (int c = 0; c < 25; ++c) {
        float m = 0.f;
        for (int k = 0; k < 12; ++k) m += hv[k] * cb[k * 100 + c];   // codebook [12,100]
        mul[c] = m;
    }
    float best = -INFINITY; int bi = 0;
    for (int c = 0; c < 50; ++c) {
        float v = (c < 25) ? mul[c] : -mul[c - 25];
        if (v > best) { best = v; bi = c; }   // strict > => first max, like jnp.argmax
    }
    bin_idx[i] = bi;
    atomicAdd(&counts[bi], 1);
}

// ---------------- stable argsort-by-bin via wave64 ballot (one wave per bin) --------
__global__ __launch_bounds__(64) void scatter_kernel(
    const int* __restrict__ bin_idx, const int* __restrict__ counts,
    int* __restrict__ order) {
    int b = blockIdx.x;
    int lane = threadIdx.x;
    int offs = 0;
    for (int q = 0; q < b; ++q) offs += counts[q];
    unsigned long long below = (lane == 63) ? ~0ULL >> 1 : ((1ULL << (lane + 1)) - 1) >> 1;
    // below = mask of lanes strictly less than `lane`
    below = (lane == 0) ? 0ULL : ((~0ULL) >> (64 - lane));
    for (int base = 0; base < NN; base += 64) {
        int i = base + lane;
        bool active = (i < NN) && (bin_idx[i] == b);
        unsigned long long m = __ballot(active);
        if (active) order[offs + __popcll(m & below)] = i;
        offs += __popcll(m);
    }
}

// ---------------- fused graph mega-kernel: one block per 100-node chunk -------------
// kNN (gram+sigmoid+top16) -> deg/dis -> hW -> GCNConv -> GraphConv -> leaky -> gc_out
__global__ __launch_bounds__(256) void graph_kernel(
    const float* __restrict__ h, const int* __restrict__ order,
    const float* __restrict__ gcn_W, const float* __restrict__ gcn_b,
    const float* __restrict__ Wrel, const float* __restrict__ brel,
    const float* __restrict__ Wroot, float* __restrict__ gc_out) {
    int p = blockIdx.x, tid = threadIdx.x;
    __shared__ float s_h[BINSZ * 12];
    __shared__ int   s_nodes[BINSZ];
    __shared__ int   s_ti[BINSZ * KNN];
    __shared__ float s_ew[BINSZ * KNN];
    __shared__ float s_deg[BINSZ];
    __shared__ float s_dis[BINSZ];
    __shared__ float s_hW[BINSZ * 32];
    __shared__ float s_gcn[BINSZ * 32];
    __shared__ float s_agg[BINSZ * 32];

    if (tid < BINSZ) s_nodes[tid] = order[p * BINSZ + tid];
    __syncthreads();
    for (int t = tid; t < BINSZ * 12; t += 256) {
        int i = t / 12, k = t - i * 12;
        s_h[t] = h[s_nodes[i] * 12 + k];
    }
    if (tid < BINSZ) s_deg[tid] = 1.0f;              // self-loop weight
    for (int t = tid; t < BINSZ * 32; t += 256) s_agg[t] = 0.f;
    __syncthreads();

    // per-row gram + sigmoid + top-16 (ties -> lower j wins, like lax.top_k)
    if (tid < BINSZ) {
        float xi[12];
        for (int k = 0; k < 12; ++k) xi[k] = s_h[tid * 12 + k];
        float tv[KNN]; int ti[KNN];
        for (int k = 0; k < KNN; ++k) { tv[k] = -1e30f; ti[k] = 0; }
        for (int j = 0; j < BINSZ; ++j) {
            float d = 0.f;
            for (int k = 0; k < 12; ++k) d += xi[k] * s_h[j * 12 + k];
            float v = 1.f / (1.f + expf(-d));
            if (v > tv[KNN - 1]) {
                int pos = KNN - 1;
                while (pos > 0 && v > tv[pos - 1]) {
                    tv[pos] = tv[pos - 1]; ti[pos] = ti[pos - 1]; pos--;
                }
                tv[pos] = v; ti[pos] = j;
            }
        }
        for (int k = 0; k < KNN; ++k) {
            s_ti[tid * KNN + k] = ti[k];
            s_ew[tid * KNN + k] = tv[k];
        }
    }
    __syncthreads();

    // degree: deg[dst] += ew  (edge e: src = e>>4, dst = s_ti[e])
    for (int e = tid; e < BINSZ * KNN; e += 256)
        atomicAdd(&s_deg[s_ti[e]], s_ew[e]);
    __syncthreads();
    if (tid < BINSZ) s_dis[tid] = 1.0f / sqrtf(s_deg[tid]);   // deg >= 1 always

    // hW = leaky(h) @ gcn_W   (no bias)
    for (int t = tid; t < BINSZ * 32; t += 256) {
        int i = t >> 5, c = t & 31;
        float acc = 0.f;
        for (int k = 0; k < 12; ++k) acc += lrelu(s_h[i * 12 + k]) * gcn_W[k * 32 + c];
        s_hW[t] = acc;
    }
    __syncthreads();

    // GCN: self-loop + bias
    for (int t = tid; t < BINSZ * 32; t += 256) {
        int i = t >> 5, c = t & 31;
        s_gcn[t] = s_dis[i] * s_dis[i] * s_hW[t] + gcn_b[c];
    }
    __syncthreads();
    // GCN edges: gcn[dst] += dis[src]*ew*dis[dst] * hW[src]
    for (int t = tid; t < BINSZ * KNN * 32; t += 256) {
        int e = t >> 5, c = t & 31;
        int srcl = e >> 4, dstl = s_ti[e];
        float coef = s_dis[srcl] * s_ew[e] * s_dis[dstl];
        atomicAdd(&s_gcn[dstl * 32 + c], coef * s_hW[srcl * 32 + c]);
    }
    __syncthreads();
    // GraphConv agg: agg[dst] += ew * gcn[src]
    for (int t = tid; t < BINSZ * KNN * 32; t += 256) {
        int e = t >> 5, c = t & 31;
        int srcl = e >> 4, dstl = s_ti[e];
        atomicAdd(&s_agg[dstl * 32 + c], s_ew[e] * s_gcn[srcl * 32 + c]);
    }
    __syncthreads();
    // combine: out = leaky(agg @ Wrel + brel + gcn @ Wroot), scatter to global
    for (int t = tid; t < BINSZ * 32; t += 256) {
        int i = t >> 5, j = t & 31;
        float acc = brel[j];
        for (int k = 0; k < 32; ++k)
            acc += s_agg[i * 32 + k] * Wrel[k * 32 + j] + s_gcn[i * 32 + k] * Wroot[k * 32 + j];
        gc_out[s_nodes[i] * 32 + j] = lrelu(acc);
    }
}

// ---------------- fused nn2 + nn3: gc[5000,32] -> ids[,6] ; concat(38) -> p4[,6] ----
__global__ __launch_bounds__(128) void nn23_kernel(
    const float* __restrict__ gc,
    const float* __restrict__ A1, const float* __restrict__ ab1,
    const float* __restrict__ A2, const float* __restrict__ ab2,
    const float* __restrict__ A3, const float* __restrict__ ab3,
    const float* __restrict__ B1, const float* __restrict__ bb1,
    const float* __restrict__ B2, const float* __restrict__ bb2,
    const float* __restrict__ B3, const float* __restrict__ bb3,
    float* __restrict__ out_ids, float* __restrict__ out_p4) {
    __shared__ float s_in[MNODES * 38];       // [0:32) = gc row, [32:38) = ids
    __shared__ float s_h1[MNODES * 125];
    __shared__ float s_h2[MNODES * 125];
    int tid = threadIdx.x;
    int n0 = blockIdx.x * MNODES;
    int nmax = NN - n0; if (nmax > MNODES) nmax = MNODES;

    for (int t = tid; t < nmax * 32; t += 128) {
        int n = t >> 5, c = t & 31;
        s_in[n * 38 + c] = gc[(n0 + n) * 32 + c];
    }
    __syncthreads();
    // nn2 L1: 32 -> 125
    for (int o = tid; o < nmax * 125; o += 128) {
        int n = o / 125, j = o - n * 125;
        float acc = ab1[j];
        for (int k = 0; k < 32; ++k) acc += s_in[n * 38 + k] * A1[k * 125 + j];
        s_h1[o] = lrelu(acc);
    }
    __syncthreads();
    // nn2 L2: 125 -> 125
    for (int o = tid; o < nmax * 125; o += 128) {
        int n = o / 125, j = o - n * 125;
        float acc = ab2[j];
        for (int k = 0; k < 125; ++k) acc += s_h1[n * 125 + k] * A2[k * 125 + j];
        s_h2[o] = lrelu(acc);
    }
    __syncthreads();
    // nn2 L3: 125 -> 6 (ids), write + keep
    for (int o = tid; o < nmax * 6; o += 128) {
        int n = o / 6, j = o - n * 6;
        float acc = ab3[j];
        for (int k = 0; k < 125; ++k) acc += s_h2[n * 125 + k] * A3[k * 6 + j];
        out_ids[(n0 + n) * 6 + j] = acc;
        s_in[n * 38 + 32 + j] = acc;
    }
    __syncthreads();
    // nn3 L1: 38 -> 125
    for (int o = tid; o < nmax * 125; o += 128) {
        int n = o / 125, j = o - n * 125;
        float acc = bb1[j];
        for (int k = 0; k < 38; ++k) acc += s_in[n * 38 + k] * B1[k * 125 + j];
        s_h1[o] = lrelu(acc);
    }
    __syncthreads();
    // nn3 L2: 125 -> 125
    for (int o = tid; o < nmax * 125; o += 128) {
        int n = o / 125, j = o - n * 125;
        float acc = bb2[j];
        for (int k = 0; k < 125; ++k) acc += s_h1[n * 125 + k] * B2[k * 125 + j];
        s_h2[o] = lrelu(acc);
    }
    __syncthreads();
    // nn3 L3: 125 -> 6 (p4)
    for (int o = tid; o < nmax * 6; o += 128) {
        int n = o / 6, j = o - n * 6;
        float acc = bb3[j];
        for (int k = 0; k < 125; ++k) acc += s_h2[n * 125 + k] * B3[k * 6 + j];
        out_p4[(n0 + n) * 6 + j] = acc;
    }
}

static inline int cdiv(int a, int b) { return (a + b - 1) / b; }

extern "C" void kernel_launch(void* const* d_in, const int* in_sizes, int n_in,
                              void* d_out, int out_size, void* d_ws, size_t ws_size,
                              hipStream_t stream) {
    const float* x        = (const float*)d_in[0];
    const float* ygen_id  = (const float*)d_in[1];
    const float* ygen     = (const float*)d_in[2];
    const float* codebook = (const float*)d_in[3];
    const float* nn1_W1 = (const float*)d_in[4];  const float* nn1_b1 = (const float*)d_in[5];
    const float* nn1_W2 = (const float*)d_in[6];  const float* nn1_b2 = (const float*)d_in[7];
    const float* nn1_W3 = (const float*)d_in[8];  const float* nn1_b3 = (const float*)d_in[9];
    const float* gcn_W  = (const float*)d_in[10]; const float* gcn_b  = (const float*)d_in[11];
    const float* gc_Wrel = (const float*)d_in[12]; const float* gc_brel = (const float*)d_in[13];
    const float* gc_Wroot = (const float*)d_in[14];
    const float* nn2_W1 = (const float*)d_in[15]; const float* nn2_b1 = (const float*)d_in[16];
    const float* nn2_W2 = (const float*)d_in[17]; const float* nn2_b2 = (const float*)d_in[18];
    const float* nn2_W3 = (const float*)d_in[19]; const float* nn2_b3 = (const float*)d_in[20];
    const float* nn3_W1 = (const float*)d_in[21]; const float* nn3_b1 = (const float*)d_in[22];
    const float* nn3_W2 = (const float*)d_in[23]; const float* nn3_b2 = (const float*)d_in[24];
    const float* nn3_W3 = (const float*)d_in[25]; const float* nn3_b3 = (const float*)d_in[26];

    float* out = (float*)d_out;
    float* ws  = (float*)d_ws;

    // workspace layout (float offsets)
    float* h       = ws + 0;        // 60000   (5000x12, pre-leaky)
    float* gc_out  = ws + 60000;    // 160000  (5000x32)
    int*   bin_idx = (int*)(ws + 220000);  // 5000
    int*   order   = (int*)(ws + 225000);  // 5000
    int*   counts  = (int*)(ws + 230000);  // 50

    // nn1 (fused 3 layers)
    nn1_kernel<<<cdiv(NN, MNODES), 128, 0, stream>>>(
        x, nn1_W1, nn1_b1, nn1_W2, nn1_b2, nn1_W3, nn1_b3, h);

    // LSH binning
    hipMemsetAsync(counts, 0, NBINS * sizeof(int), stream);
    bin_kernel<<<cdiv(NN, 256), 256, 0, stream>>>(h, codebook, bin_idx, counts);
    scatter_kernel<<<NBINS, 64, 0, stream>>>(bin_idx, counts, order);

    // fused graph section (kNN + GCNConv + GraphConv + leaky)
    graph_kernel<<<NBINS, 256, 0, stream>>>(
        h, order, gcn_W, gcn_b, gc_Wrel, gc_brel, gc_Wroot, gc_out);

    // fused nn2 + nn3
    nn23_kernel<<<cdiv(NN, MNODES), 128, 0, stream>>>(
        gc_out,
        nn2_W1, nn2_b1, nn2_W2, nn2_b2, nn2_W3, nn2_b3,
        nn3_W1, nn3_b1, nn3_W2, nn3_b2, nn3_W3, nn3_b3,
        out, out + 30000);

    // passthrough outputs
    hipMemcpyAsync(out + 60000, ygen_id, 30000 * sizeof(float), hipMemcpyDeviceToDevice, stream);
    hipMemcpyAsync(out + 90000, ygen, 30000 * sizeof(float), hipMemcpyDeviceToDevice, stream);
}

// Round 3
// 520.560 us; speedup vs baseline: 1.6591x; 1.2504x over previous
//
#include <hip/hip_runtime.h>
#include <math.h>

#define NN 5000
#define NBINS 50
#define BINSZ 100
#define KNN 16

__device__ __forceinline__ float lrelu(float x){ return x >= 0.f ? x : 0.01f*x; }
__device__ __forceinline__ float sigm(float x){ return 1.f / (1.f + expf(-x)); }

// ---------------- fused MLP1 + LSH bin: x[5000,12] -> 125 -> 125 -> 12 (h) + bin ----
#define MNODES 16
__global__ __launch_bounds__(256) void nn1_kernel(
    const float* __restrict__ x,
    const float* __restrict__ W1, const float* __restrict__ b1,
    const float* __restrict__ W2, const float* __restrict__ b2,
    const float* __restrict__ W3, const float* __restrict__ b3,
    const float* __restrict__ cb,
    float* __restrict__ h_out, int* __restrict__ bin_idx, int* __restrict__ counts) {
    __shared__ float s_in[MNODES * 12];   // input x rows; later reused for h rows
    __shared__ float s_h1[MNODES * 125];
    __shared__ float s_h2[MNODES * 125];
    int tid = threadIdx.x;
    int n0 = blockIdx.x * MNODES;
    int nmax = NN - n0; if (nmax > MNODES) nmax = MNODES;

    for (int t = tid; t < nmax * 12; t += 256) s_in[t] = x[n0 * 12 + t];
    __syncthreads();
    // L1: 12 -> 125, leaky
    for (int o = tid; o < nmax * 125; o += 256) {
        int n = o / 125, j = o - n * 125;
        float acc = b1[j];
        #pragma unroll
        for (int k = 0; k < 12; ++k) acc += s_in[n * 12 + k] * W1[k * 125 + j];
        s_h1[o] = lrelu(acc);
    }
    __syncthreads();
    // L2: 125 -> 125, leaky
    for (int o = tid; o < nmax * 125; o += 256) {
        int n = o / 125, j = o - n * 125;
        float acc = b2[j];
        for (int k = 0; k < 125; ++k) acc += s_h1[n * 125 + k] * W2[k * 125 + j];
        s_h2[o] = lrelu(acc);
    }
    __syncthreads();
    // L3: 125 -> 12, no act; write global h and stash in s_in (reuse) for binning
    for (int o = tid; o < nmax * 12; o += 256) {
        int n = o / 12, j = o - n * 12;
        float acc = b3[j];
        for (int k = 0; k < 125; ++k) acc += s_h2[n * 125 + k] * W3[k * 12 + j];
        h_out[n0 * 12 + o] = acc;
        s_in[o] = acc;
    }
    __syncthreads();
    // LSH bin per node (jnp.argmax over [mul, -mul], first max wins)
    if (tid < nmax) {
        float hv[12];
        #pragma unroll
        for (int k = 0; k < 12; ++k) hv[k] = s_in[tid * 12 + k];
        float best = -INFINITY; int bi = 0;
        #pragma unroll 5
        for (int c = 0; c < 25; ++c) {
            float m = 0.f;
            #pragma unroll
            for (int k = 0; k < 12; ++k) m += hv[k] * cb[k * 100 + c];  // codebook [12,100]
            if (m > best) { best = m; bi = c; }
        }
        #pragma unroll 5
        for (int c = 0; c < 25; ++c) {
            float m = 0.f;
            #pragma unroll
            for (int k = 0; k < 12; ++k) m += hv[k] * cb[k * 100 + c];
            if (-m > best) { best = -m; bi = c + 25; }
        }
        bin_idx[n0 + tid] = bi;
        atomicAdd(&counts[bi], 1);
    }
}

// ---------------- stable argsort-by-bin via wave64 ballot (one wave per bin) --------
__global__ __launch_bounds__(64) void scatter_kernel(
    const int* __restrict__ bin_idx, const int* __restrict__ counts,
    int* __restrict__ order) {
    int b = blockIdx.x;
    int lane = threadIdx.x;
    int offs = 0;
    for (int q = 0; q < b; ++q) offs += counts[q];
    unsigned long long below = (lane == 0) ? 0ULL : ((~0ULL) >> (64 - lane));
    for (int base = 0; base < NN; base += 64) {
        int i = base + lane;
        bool active = (i < NN) && (bin_idx[i] == b);
        unsigned long long m = __ballot(active);
        if (active) order[offs + __popcll(m & below)] = i;
        offs += __popcll(m);
    }
}

// ---------------- fused graph mega-kernel: one block per 100-node chunk -------------
// kNN (gram+sigmoid+top16, register-resident unrolled insert) -> deg/dis -> hWd ->
// GCNConv -> GraphConv -> leaky -> gc_out
__global__ __launch_bounds__(256) void graph_kernel(
    const float* __restrict__ h, const int* __restrict__ order,
    const float* __restrict__ gcn_W, const float* __restrict__ gcn_b,
    const float* __restrict__ Wrel, const float* __restrict__ brel,
    const float* __restrict__ Wroot, float* __restrict__ gc_out) {
    int p = blockIdx.x, tid = threadIdx.x;
    __shared__ float s_h[BINSZ * 12];
    __shared__ int   s_nodes[BINSZ];
    __shared__ int   s_ti[BINSZ * KNN];
    __shared__ float s_ew[BINSZ * KNN];
    __shared__ float s_deg[BINSZ];
    __shared__ float s_dis[BINSZ];
    __shared__ float s_hWd[BINSZ * 32];   // dis[i] * (leaky(h) @ gcn_W)[i][c]
    __shared__ float s_gcn[BINSZ * 32];
    __shared__ float s_agg[BINSZ * 32];

    if (tid < BINSZ) { s_nodes[tid] = order[p * BINSZ + tid]; s_deg[tid] = 1.0f; }
    __syncthreads();
    for (int t = tid; t < BINSZ * 12; t += 256) {
        int i = t / 12, k = t - i * 12;
        s_h[t] = h[s_nodes[i] * 12 + k];
    }
    for (int t = tid; t < BINSZ * 32; t += 256) s_agg[t] = 0.f;
    __syncthreads();

    // per-row gram + sigmoid + top-16; ties -> lower j (matches lax.top_k).
    // Fully unrolled bubble-insert: static indexing only => stays in VGPRs.
    if (tid < BINSZ) {
        float xi[12];
        #pragma unroll
        for (int k = 0; k < 12; ++k) xi[k] = s_h[tid * 12 + k];
        float tv[KNN]; int ti[KNN];
        #pragma unroll
        for (int k = 0; k < KNN; ++k) { tv[k] = -1e30f; ti[k] = 0; }
        for (int j = 0; j < BINSZ; ++j) {
            float d = 0.f;
            #pragma unroll
            for (int k = 0; k < 12; ++k) d += xi[k] * s_h[j * 12 + k];
            float v = sigm(d);
            if (v > tv[KNN - 1]) {
                int vi = j;
                #pragma unroll
                for (int k = 0; k < KNN; ++k) {
                    bool gt = v > tv[k];           // strict: incumbent (lower j) stays ahead
                    float nv = gt ? v : tv[k];  int ni = gt ? vi : ti[k];
                    float ov = gt ? tv[k] : v;  int oi = gt ? ti[k] : vi;
                    tv[k] = nv; ti[k] = ni; v = ov; vi = oi;
                }
            }
        }
        #pragma unroll
        for (int k = 0; k < KNN; ++k) {
            s_ti[tid * KNN + k] = ti[k];
            s_ew[tid * KNN + k] = tv[k];
        }
    }
    __syncthreads();

    // degree: deg[dst] += ew   (edge e: src = e>>4, dst = s_ti[e]); self-loop already 1
    for (int e = tid; e < BINSZ * KNN; e += 256)
        atomicAdd(&s_deg[s_ti[e]], s_ew[e]);
    __syncthreads();
    if (tid < BINSZ) s_dis[tid] = 1.0f / sqrtf(s_deg[tid]);   // deg >= 1 always

    // hWd[i][c] = dis[i] * sum_k leaky(h[i,k]) * gcn_W[k,c]
    __syncthreads();
    for (int t = tid; t < BINSZ * 32; t += 256) {
        int i = t >> 5, c = t & 31;
        float acc = 0.f;
        #pragma unroll
        for (int k = 0; k < 12; ++k) acc += lrelu(s_h[i * 12 + k]) * gcn_W[k * 32 + c];
        s_hWd[t] = s_dis[i] * acc;
    }
    __syncthreads();

    // GCN self-loop + bias: dis[i]^2 * hW = dis[i] * hWd
    for (int t = tid; t < BINSZ * 32; t += 256) {
        int i = t >> 5, c = t & 31;
        s_gcn[t] = s_dis[i] * s_hWd[t] + gcn_b[c];
    }
    __syncthreads();
    // GCN edges: gcn[dst] += dis[src]*ew*dis[dst]*hW[src] = ew*dis[dst]*hWd[src]
    for (int t = tid; t < BINSZ * KNN * 32; t += 256) {
        int e = t >> 5, c = t & 31;
        int srcl = e >> 4, dstl = s_ti[e];
        atomicAdd(&s_gcn[dstl * 32 + c], s_ew[e] * s_dis[dstl] * s_hWd[srcl * 32 + c]);
    }
    __syncthreads();
    // GraphConv agg: agg[dst] += ew * gcn[src]
    for (int t = tid; t < BINSZ * KNN * 32; t += 256) {
        int e = t >> 5, c = t & 31;
        int srcl = e >> 4, dstl = s_ti[e];
        atomicAdd(&s_agg[dstl * 32 + c], s_ew[e] * s_gcn[srcl * 32 + c]);
    }
    __syncthreads();
    // combine: out = leaky(agg @ Wrel + brel + gcn @ Wroot)
    for (int t = tid; t < BINSZ * 32; t += 256) {
        int i = t >> 5, j = t & 31;
        float acc = brel[j];
        #pragma unroll 8
        for (int k = 0; k < 32; ++k)
            acc += s_agg[i * 32 + k] * Wrel[k * 32 + j] + s_gcn[i * 32 + k] * Wroot[k * 32 + j];
        gc_out[s_nodes[i] * 32 + j] = lrelu(acc);
    }
}

// ---------------- fused nn2 + nn3: gc[5000,32] -> ids[,6] ; concat(38) -> p4[,6] ----
__global__ __launch_bounds__(256) void nn23_kernel(
    const float* __restrict__ gc,
    const float* __restrict__ A1, const float* __restrict__ ab1,
    const float* __restrict__ A2, const float* __restrict__ ab2,
    const float* __restrict__ A3, const float* __restrict__ ab3,
    const float* __restrict__ B1, const float* __restrict__ bb1,
    const float* __restrict__ B2, const float* __restrict__ bb2,
    const float* __restrict__ B3, const float* __restrict__ bb3,
    float* __restrict__ out_ids, float* __restrict__ out_p4) {
    __shared__ float s_in[MNODES * 38];       // [0:32) = gc row, [32:38) = ids
    __shared__ float s_h1[MNODES * 125];
    __shared__ float s_h2[MNODES * 125];
    int tid = threadIdx.x;
    int n0 = blockIdx.x * MNODES;
    int nmax = NN - n0; if (nmax > MNODES) nmax = MNODES;

    for (int t = tid; t < nmax * 32; t += 256) {
        int n = t >> 5, c = t & 31;
        s_in[n * 38 + c] = gc[(n0 + n) * 32 + c];
    }
    __syncthreads();
    // nn2 L1: 32 -> 125
    for (int o = tid; o < nmax * 125; o += 256) {
        int n = o / 125, j = o - n * 125;
        float acc = ab1[j];
        #pragma unroll 8
        for (int k = 0; k < 32; ++k) acc += s_in[n * 38 + k] * A1[k * 125 + j];
        s_h1[o] = lrelu(acc);
    }
    __syncthreads();
    // nn2 L2: 125 -> 125
    for (int o = tid; o < nmax * 125; o += 256) {
        int n = o / 125, j = o - n * 125;
        float acc = ab2[j];
        for (int k = 0; k < 125; ++k) acc += s_h1[n * 125 + k] * A2[k * 125 + j];
        s_h2[o] = lrelu(acc);
    }
    __syncthreads();
    // nn2 L3: 125 -> 6 (ids), write + keep for concat
    for (int o = tid; o < nmax * 6; o += 256) {
        int n = o / 6, j = o - n * 6;
        float acc = ab3[j];
        for (int k = 0; k < 125; ++k) acc += s_h2[n * 125 + k] * A3[k * 6 + j];
        out_ids[(n0 + n) * 6 + j] = acc;
        s_in[n * 38 + 32 + j] = acc;
    }
    __syncthreads();
    // nn3 L1: 38 -> 125
    for (int o = tid; o < nmax * 125; o += 256) {
        int n = o / 125, j = o - n * 125;
        float acc = bb1[j];
        #pragma unroll 2
        for (int k = 0; k < 38; ++k) acc += s_in[n * 38 + k] * B1[k * 125 + j];
        s_h1[o] = lrelu(acc);
    }
    __syncthreads();
    // nn3 L2: 125 -> 125
    for (int o = tid; o < nmax * 125; o += 256) {
        int n = o / 125, j = o - n * 125;
        float acc = bb2[j];
        for (int k = 0; k < 125; ++k) acc += s_h1[n * 125 + k] * B2[k * 125 + j];
        s_h2[o] = lrelu(acc);
    }
    __syncthreads();
    // nn3 L3: 125 -> 6 (p4)
    for (int o = tid; o < nmax * 6; o += 256) {
        int n = o / 6, j = o - n * 6;
        float acc = bb3[j];
        for (int k = 0; k < 125; ++k) acc += s_h2[n * 125 + k] * B3[k * 6 + j];
        out_p4[(n0 + n) * 6 + j] = acc;
    }
}

// ---------------- passthrough: out[60000:90000]=ygen_id, out[90000:120000]=ygen -----
__global__ __launch_bounds__(256) void copy_kernel(
    const float* __restrict__ a, const float* __restrict__ b, float* __restrict__ out) {
    int t = blockIdx.x * blockDim.x + threadIdx.x;
    if (t < 30000) out[60000 + t] = a[t];
    else if (t < 60000) out[60000 + t] = b[t - 30000];
}

static inline int cdiv(int a, int b) { return (a + b - 1) / b; }

extern "C" void kernel_launch(void* const* d_in, const int* in_sizes, int n_in,
                              void* d_out, int out_size, void* d_ws, size_t ws_size,
                              hipStream_t stream) {
    const float* x        = (const float*)d_in[0];
    const float* ygen_id  = (const float*)d_in[1];
    const float* ygen     = (const float*)d_in[2];
    const float* codebook = (const float*)d_in[3];
    const float* nn1_W1 = (const float*)d_in[4];  const float* nn1_b1 = (const float*)d_in[5];
    const float* nn1_W2 = (const float*)d_in[6];  const float* nn1_b2 = (const float*)d_in[7];
    const float* nn1_W3 = (const float*)d_in[8];  const float* nn1_b3 = (const float*)d_in[9];
    const float* gcn_W  = (const float*)d_in[10]; const float* gcn_b  = (const float*)d_in[11];
    const float* gc_Wrel = (const float*)d_in[12]; const float* gc_brel = (const float*)d_in[13];
    const float* gc_Wroot = (const float*)d_in[14];
    const float* nn2_W1 = (const float*)d_in[15]; const float* nn2_b1 = (const float*)d_in[16];
    const float* nn2_W2 = (const float*)d_in[17]; const float* nn2_b2 = (const float*)d_in[18];
    const float* nn2_W3 = (const float*)d_in[19]; const float* nn2_b3 = (const float*)d_in[20];
    const float* nn3_W1 = (const float*)d_in[21]; const float* nn3_b1 = (const float*)d_in[22];
    const float* nn3_W2 = (const float*)d_in[23]; const float* nn3_b2 = (const float*)d_in[24];
    const float* nn3_W3 = (const float*)d_in[25]; const float* nn3_b3 = (const float*)d_in[26];

    float* out = (float*)d_out;
    float* ws  = (float*)d_ws;

    // workspace layout (float offsets)
    float* h       = ws + 0;        // 60000   (5000x12, pre-leaky)
    float* gc_out  = ws + 60000;    // 160000  (5000x32)
    int*   bin_idx = (int*)(ws + 220000);  // 5000
    int*   order   = (int*)(ws + 225000);  // 5000
    int*   counts  = (int*)(ws + 230000);  // 50

    hipMemsetAsync(counts, 0, NBINS * sizeof(int), stream);

    // nn1 (fused 3 layers + LSH bin assignment)
    nn1_kernel<<<cdiv(NN, MNODES), 256, 0, stream>>>(
        x, nn1_W1, nn1_b1, nn1_W2, nn1_b2, nn1_W3, nn1_b3, codebook,
        h, bin_idx, counts);

    // stable counting-sort scatter
    scatter_kernel<<<NBINS, 64, 0, stream>>>(bin_idx, counts, order);

    // fused graph section (kNN + GCNConv + GraphConv + leaky)
    graph_kernel<<<NBINS, 256, 0, stream>>>(
        h, order, gcn_W, gcn_b, gc_Wrel, gc_brel, gc_Wroot, gc_out);

    // fused nn2 + nn3
    nn23_kernel<<<cdiv(NN, MNODES), 256, 0, stream>>>(
        gc_out,
        nn2_W1, nn2_b1, nn2_W2, nn2_b2, nn2_W3, nn2_b3,
        nn3_W1, nn3_b1, nn3_W2, nn3_b2, nn3_W3, nn3_b3,
        out, out + 30000);

    // passthrough outputs
    copy_kernel<<<cdiv(60000, 256), 256, 0, stream>>>(ygen_id, ygen, out);
}

// Round 4
// 324.804 us; speedup vs baseline: 2.6590x; 1.6027x over previous
//
#include <hip/hip_runtime.h>
#include <math.h>

#define NN 5000
#define NBINS 50
#define BINSZ 100
#define KNN 16
#define BPAD 104          // padded M row length (halves); 208 B row stride (16B-aligned)
#define MN 16             // nodes per block in MLP kernels

typedef _Float16 half8 __attribute__((ext_vector_type(8)));

__device__ __forceinline__ float lrelu(float x){ return x >= 0.f ? x : 0.01f*x; }

// =================== fused MLP1 + LSH bin: x[5000,12] -> 125 -> 125 -> 12 ===========
// Transposed LDS activations [k][n]; thread j owns output column j, 16 node-accs in regs.
__global__ __launch_bounds__(128) void nn1_kernel(
    const float* __restrict__ x,
    const float* __restrict__ W1, const float* __restrict__ b1,
    const float* __restrict__ W2, const float* __restrict__ b2,
    const float* __restrict__ W3, const float* __restrict__ b3,
    const float* __restrict__ cb,
    float* __restrict__ h_out, int* __restrict__ bin_idx, int* __restrict__ counts) {
    __shared__ float sA[125 * MN];
    __shared__ float sB[125 * MN];
    int tid = threadIdx.x;
    int n0 = blockIdx.x * MN;
    int nmax = NN - n0; if (nmax > MN) nmax = MN;

    // load x transposed: sA[k][n]
    for (int t = tid; t < 12 * MN; t += 128) {
        int k = t >> 4, n = t & 15;
        sA[k * MN + n] = (n < nmax) ? x[(n0 + n) * 12 + k] : 0.f;
    }
    __syncthreads();
    // L1: 12 -> 125, leaky  (sA -> sB)
    if (tid < 125) {
        int j = tid;
        float acc[MN];
        #pragma unroll
        for (int n = 0; n < MN; ++n) acc[n] = b1[j];
        #pragma unroll
        for (int k = 0; k < 12; ++k) {
            float w = W1[k * 125 + j];
            const float4* hp = (const float4*)&sA[k * MN];
            float4 h0 = hp[0], h1 = hp[1], h2 = hp[2], h3 = hp[3];
            acc[0]+=h0.x*w; acc[1]+=h0.y*w; acc[2]+=h0.z*w; acc[3]+=h0.w*w;
            acc[4]+=h1.x*w; acc[5]+=h1.y*w; acc[6]+=h1.z*w; acc[7]+=h1.w*w;
            acc[8]+=h2.x*w; acc[9]+=h2.y*w; acc[10]+=h2.z*w; acc[11]+=h2.w*w;
            acc[12]+=h3.x*w; acc[13]+=h3.y*w; acc[14]+=h3.z*w; acc[15]+=h3.w*w;
        }
        #pragma unroll
        for (int n = 0; n < MN; ++n) sB[j * MN + n] = lrelu(acc[n]);
    }
    __syncthreads();
    // L2: 125 -> 125, leaky (sB -> sA)
    if (tid < 125) {
        int j = tid;
        float acc[MN];
        #pragma unroll
        for (int n = 0; n < MN; ++n) acc[n] = b2[j];
        for (int k = 0; k < 125; ++k) {
            float w = W2[k * 125 + j];
            const float4* hp = (const float4*)&sB[k * MN];
            float4 h0 = hp[0], h1 = hp[1], h2 = hp[2], h3 = hp[3];
            acc[0]+=h0.x*w; acc[1]+=h0.y*w; acc[2]+=h0.z*w; acc[3]+=h0.w*w;
            acc[4]+=h1.x*w; acc[5]+=h1.y*w; acc[6]+=h1.z*w; acc[7]+=h1.w*w;
            acc[8]+=h2.x*w; acc[9]+=h2.y*w; acc[10]+=h2.z*w; acc[11]+=h2.w*w;
            acc[12]+=h3.x*w; acc[13]+=h3.y*w; acc[14]+=h3.z*w; acc[15]+=h3.w*w;
        }
        #pragma unroll
        for (int n = 0; n < MN; ++n) sA[j * MN + n] = lrelu(acc[n]);
    }
    __syncthreads();
    // L3: 125 -> 12, no act (sA -> global h + sB transposed for binning)
    if (tid < 12) {
        int j = tid;
        float acc[MN];
        #pragma unroll
        for (int n = 0; n < MN; ++n) acc[n] = b3[j];
        for (int k = 0; k < 125; ++k) {
            float w = W3[k * 12 + j];
            const float4* hp = (const float4*)&sA[k * MN];
            float4 h0 = hp[0], h1 = hp[1], h2 = hp[2], h3 = hp[3];
            acc[0]+=h0.x*w; acc[1]+=h0.y*w; acc[2]+=h0.z*w; acc[3]+=h0.w*w;
            acc[4]+=h1.x*w; acc[5]+=h1.y*w; acc[6]+=h1.z*w; acc[7]+=h1.w*w;
            acc[8]+=h2.x*w; acc[9]+=h2.y*w; acc[10]+=h2.z*w; acc[11]+=h2.w*w;
            acc[12]+=h3.x*w; acc[13]+=h3.y*w; acc[14]+=h3.z*w; acc[15]+=h3.w*w;
        }
        for (int n = 0; n < nmax; ++n) h_out[(n0 + n) * 12 + j] = acc[n];
        #pragma unroll
        for (int n = 0; n < MN; ++n) sB[j * MN + n] = acc[n];
    }
    __syncthreads();
    // LSH bin per node (argmax over [mul, -mul], first max wins)
    if (tid < nmax) {
        int n = tid;
        float hv[12];
        #pragma unroll
        for (int k = 0; k < 12; ++k) hv[k] = sB[k * MN + n];
        float best = -INFINITY; int bi = 0;
        for (int c = 0; c < 25; ++c) {
            float m = 0.f;
            #pragma unroll
            for (int k = 0; k < 12; ++k) m += hv[k] * cb[k * 100 + c];   // codebook [12,100]
            if (m > best) { best = m; bi = c; }
        }
        for (int c = 0; c < 25; ++c) {
            float m = 0.f;
            #pragma unroll
            for (int k = 0; k < 12; ++k) m += hv[k] * cb[k * 100 + c];
            if (-m > best) { best = -m; bi = c + 25; }
        }
        bin_idx[n0 + n] = bi;
        atomicAdd(&counts[bi], 1);
    }
}

// =================== stable argsort-by-bin via wave64 ballot ========================
__global__ __launch_bounds__(64) void scatter_kernel(
    const int* __restrict__ bin_idx, const int* __restrict__ counts,
    int* __restrict__ order) {
    int b = blockIdx.x;
    int lane = threadIdx.x;
    int offs = 0;
    for (int q = 0; q < b; ++q) offs += counts[q];
    unsigned long long below = (lane == 0) ? 0ULL : ((~0ULL) >> (64 - lane));
    for (int base = 0; base < NN; base += 64) {
        int i = base + lane;
        bool active = (i < NN) && (bin_idx[i] == b);
        unsigned long long m = __ballot(active);
        if (active) order[offs + __popcll(m & below)] = i;
        offs += __popcll(m);
    }
}

// =================== fused graph mega-kernel (dense fp16 edge-matrix form) ==========
// kNN -> M[dst][src] (fp16, LDS) -> deg/dis = rowsum -> hWd -> gcn = M*hWd (scaled)
// -> agg = M*gcn -> combine -> gc_out.  No LDS atomics, no indirection in hot loops.
__global__ __launch_bounds__(256) void graph_kernel(
    const float* __restrict__ h, const int* __restrict__ order,
    const float* __restrict__ gcn_W, const float* __restrict__ gcn_b,
    const float* __restrict__ Wrel, const float* __restrict__ brel,
    const float* __restrict__ Wroot, float* __restrict__ gc_out) {
    __shared__ _Float16 M[BINSZ * BPAD];    // 20800 B, M[d*BPAD+s]
    __shared__ float s_h[BINSZ * 12];       // 4800
    __shared__ int   s_nodes[BINSZ];        // 400
    __shared__ float s_dis[BINSZ];          // 400
    __shared__ float s_A[BPAD * 32];        // 13312  hWd; later reused as agg
    __shared__ float s_G[BPAD * 32];        // 13312  gcn
    int p = blockIdx.x, tid = threadIdx.x;

    if (tid < BINSZ) s_nodes[tid] = order[p * BINSZ + tid];
    // zero M (incl. padding) as ints
    for (int t = tid; t < BINSZ * BPAD / 2; t += 256) ((int*)M)[t] = 0;
    // zero pad rows 100..103 of s_A and s_G
    if (tid < 128) { s_A[BINSZ * 32 + tid] = 0.f; s_G[BINSZ * 32 + tid] = 0.f; }
    __syncthreads();
    for (int t = tid; t < BINSZ * 12; t += 256) {
        int i = t / 12, k = t - i * 12;
        s_h[t] = h[s_nodes[i] * 12 + k];
    }
    __syncthreads();

    // --- gram + sigmoid + top-16 (ties -> lower j), write column tid of M -----------
    if (tid < BINSZ) {
        const float4* xp = (const float4*)&s_h[tid * 12];
        float4 x0 = xp[0], x1 = xp[1], x2 = xp[2];
        float tv[KNN]; int ti[KNN];
        #pragma unroll
        for (int k = 0; k < KNN; ++k) { tv[k] = -1e30f; ti[k] = 0; }
        for (int j = 0; j < BINSZ; ++j) {
            const float4* ap = (const float4*)&s_h[j * 12];
            float4 a0 = ap[0], a1 = ap[1], a2 = ap[2];
            float d = x0.x*a0.x + x0.y*a0.y + x0.z*a0.z + x0.w*a0.w
                    + x1.x*a1.x + x1.y*a1.y + x1.z*a1.z + x1.w*a1.w
                    + x2.x*a2.x + x2.y*a2.y + x2.z*a2.z + x2.w*a2.w;
            float v = 1.f / (1.f + expf(-d));
            if (v > tv[KNN - 1]) {
                int vi = j;
                #pragma unroll
                for (int k = 0; k < KNN; ++k) {
                    bool gt = v > tv[k];
                    float nv = gt ? v : tv[k];  int ni = gt ? vi : ti[k];
                    float ov = gt ? tv[k] : v;  int oi = gt ? ti[k] : vi;
                    tv[k] = nv; ti[k] = ni; v = ov; vi = oi;
                }
            }
        }
        #pragma unroll
        for (int k = 0; k < KNN; ++k)
            M[ti[k] * BPAD + tid] = (_Float16)tv[k];   // edge tid -> ti[k]
    }
    __syncthreads();

    // --- degree (rowsum of M) + dis -------------------------------------------------
    if (tid < BINSZ) {
        float dsum = 1.0f;   // self-loop
        #pragma unroll 13
        for (int sc = 0; sc < 13; ++sc) {
            half8 m = *(const half8*)&M[tid * BPAD + sc * 8];
            dsum += (float)m[0] + (float)m[1] + (float)m[2] + (float)m[3]
                  + (float)m[4] + (float)m[5] + (float)m[6] + (float)m[7];
        }
        s_dis[tid] = 1.0f / sqrtf(dsum);
    }
    __syncthreads();

    // --- hWd[i][c] = dis[i] * (leaky(h[i]) @ gcn_W)[c] ------------------------------
    for (int t = tid; t < BINSZ * 32; t += 256) {
        int i = t >> 5, c = t & 31;
        float acc = 0.f;
        #pragma unroll
        for (int k = 0; k < 12; ++k) acc += lrelu(s_h[i * 12 + k]) * gcn_W[k * 32 + c];
        s_A[t] = s_dis[i] * acc;
    }
    __syncthreads();

    // --- mm1: gcn[d][c] = dis[d]*(sum_s M[d][s]*hWd[s][c] + hWd[d][c]) + b[c] -------
    {
        int c = tid & 31, g = tid >> 5;
        int nr = (g < 4) ? 13 : 12;
        float acc[13];
        #pragma unroll
        for (int r = 0; r < 13; ++r) acc[r] = 0.f;
        for (int sc = 0; sc < 13; ++sc) {
            float hv[8];
            #pragma unroll
            for (int q = 0; q < 8; ++q) hv[q] = s_A[(sc * 8 + q) * 32 + c];
            for (int r = 0; r < nr; ++r) {
                int d = g + 8 * r;
                half8 m = *(const half8*)&M[d * BPAD + sc * 8];
                #pragma unroll
                for (int q = 0; q < 8; ++q) acc[r] += (float)m[q] * hv[q];
            }
        }
        float bc = gcn_b[c];
        for (int r = 0; r < nr; ++r) {
            int d = g + 8 * r;
            s_G[d * 32 + c] = s_dis[d] * (acc[r] + s_A[d * 32 + c]) + bc;
        }
    }
    __syncthreads();

    // --- mm2: agg[d][c] = sum_s M[d][s]*gcn[s][c]  (into s_A, hWd dead) -------------
    {
        int c = tid & 31, g = tid >> 5;
        int nr = (g < 4) ? 13 : 12;
        float acc[13];
        #pragma unroll
        for (int r = 0; r < 13; ++r) acc[r] = 0.f;
        for (int sc = 0; sc < 13; ++sc) {
            float hv[8];
            #pragma unroll
            for (int q = 0; q < 8; ++q) hv[q] = s_G[(sc * 8 + q) * 32 + c];
            for (int r = 0; r < nr; ++r) {
                int d = g + 8 * r;
                half8 m = *(const half8*)&M[d * BPAD + sc * 8];
                #pragma unroll
                for (int q = 0; q < 8; ++q) acc[r] += (float)m[q] * hv[q];
            }
        }
        __syncthreads();   // ensure all mm2 reads of s_A-era data done? (s_A unread in mm2; barrier guards s_A writes vs mm1 epilogue reads)
        for (int r = 0; r < nr; ++r) {
            int d = g + 8 * r;
            s_A[d * 32 + c] = acc[r];
        }
    }
    __syncthreads();

    // --- combine: out = leaky(agg @ Wrel + brel + gcn @ Wroot) ----------------------
    for (int t = tid; t < BINSZ * 32; t += 256) {
        int i = t >> 5, j = t & 31;
        float acc = brel[j];
        #pragma unroll 8
        for (int k = 0; k < 32; ++k)
            acc += s_A[i * 32 + k] * Wrel[k * 32 + j] + s_G[i * 32 + k] * Wroot[k * 32 + j];
        gc_out[s_nodes[i] * 32 + j] = lrelu(acc);
    }
}

// =================== fused nn2 + nn3 (transposed LDS, column threads) ===============
__global__ __launch_bounds__(128) void nn23_kernel(
    const float* __restrict__ gc,
    const float* __restrict__ A1, const float* __restrict__ ab1,
    const float* __restrict__ A2, const float* __restrict__ ab2,
    const float* __restrict__ A3, const float* __restrict__ ab3,
    const float* __restrict__ B1, const float* __restrict__ bb1,
    const float* __restrict__ B2, const float* __restrict__ bb2,
    const float* __restrict__ B3, const float* __restrict__ bb3,
    float* __restrict__ out_ids, float* __restrict__ out_p4) {
    __shared__ float sIN[38 * MN];     // [k][n]; rows 32..37 = nn2 output (ids)
    __shared__ float sA[125 * MN];
    __shared__ float sB[125 * MN];
    int tid = threadIdx.x;
    int n0 = blockIdx.x * MN;
    int nmax = NN - n0; if (nmax > MN) nmax = MN;

    for (int t = tid; t < 32 * MN; t += 128) {
        int k = t >> 4, n = t & 15;
        sIN[k * MN + n] = (n < nmax) ? gc[(n0 + n) * 32 + k] : 0.f;
    }
    __syncthreads();
    // nn2 L1: 32 -> 125
    if (tid < 125) {
        int j = tid;
        float acc[MN];
        #pragma unroll
        for (int n = 0; n < MN; ++n) acc[n] = ab1[j];
        for (int k = 0; k < 32; ++k) {
            float w = A1[k * 125 + j];
            const float4* hp = (const float4*)&sIN[k * MN];
            float4 h0 = hp[0], h1 = hp[1], h2 = hp[2], h3 = hp[3];
            acc[0]+=h0.x*w; acc[1]+=h0.y*w; acc[2]+=h0.z*w; acc[3]+=h0.w*w;
            acc[4]+=h1.x*w; acc[5]+=h1.y*w; acc[6]+=h1.z*w; acc[7]+=h1.w*w;
            acc[8]+=h2.x*w; acc[9]+=h2.y*w; acc[10]+=h2.z*w; acc[11]+=h2.w*w;
            acc[12]+=h3.x*w; acc[13]+=h3.y*w; acc[14]+=h3.z*w; acc[15]+=h3.w*w;
        }
        #pragma unroll
        for (int n = 0; n < MN; ++n) sA[j * MN + n] = lrelu(acc[n]);
    }
    __syncthreads();
    // nn2 L2: 125 -> 125
    if (tid < 125) {
        int j = tid;
        float acc[MN];
        #pragma unroll
        for (int n = 0; n < MN; ++n) acc[n] = ab2[j];
        for (int k = 0; k < 125; ++k) {
            float w = A2[k * 125 + j];
            const float4* hp = (const float4*)&sA[k * MN];
            float4 h0 = hp[0], h1 = hp[1], h2 = hp[2], h3 = hp[3];
            acc[0]+=h0.x*w; acc[1]+=h0.y*w; acc[2]+=h0.z*w; acc[3]+=h0.w*w;
            acc[4]+=h1.x*w; acc[5]+=h1.y*w; acc[6]+=h1.z*w; acc[7]+=h1.w*w;
            acc[8]+=h2.x*w; acc[9]+=h2.y*w; acc[10]+=h2.z*w; acc[11]+=h2.w*w;
            acc[12]+=h3.x*w; acc[13]+=h3.y*w; acc[14]+=h3.z*w; acc[15]+=h3.w*w;
        }
        #pragma unroll
        for (int n = 0; n < MN; ++n) sB[j * MN + n] = lrelu(acc[n]);
    }
    __syncthreads();
    // nn2 L3: 125 -> 6 (ids)
    if (tid < 6) {
        int j = tid;
        float acc[MN];
        #pragma unroll
        for (int n = 0; n < MN; ++n) acc[n] = ab3[j];
        for (int k = 0; k < 125; ++k) {
            float w = A3[k * 6 + j];
            const float4* hp = (const float4*)&sB[k * MN];
            float4 h0 = hp[0], h1 = hp[1], h2 = hp[2], h3 = hp[3];
            acc[0]+=h0.x*w; acc[1]+=h0.y*w; acc[2]+=h0.z*w; acc[3]+=h0.w*w;
            acc[4]+=h1.x*w; acc[5]+=h1.y*w; acc[6]+=h1.z*w; acc[7]+=h1.w*w;
            acc[8]+=h2.x*w; acc[9]+=h2.y*w; acc[10]+=h2.z*w; acc[11]+=h2.w*w;
            acc[12]+=h3.x*w; acc[13]+=h3.y*w; acc[14]+=h3.z*w; acc[15]+=h3.w*w;
        }
        for (int n = 0; n < nmax; ++n) out_ids[(n0 + n) * 6 + j] = acc[n];
        #pragma unroll
        for (int n = 0; n < MN; ++n) sIN[(32 + j) * MN + n] = acc[n];
    }
    __syncthreads();
    // nn3 L1: 38 -> 125
    if (tid < 125) {
        int j = tid;
        float acc[MN];
        #pragma unroll
        for (int n = 0; n < MN; ++n) acc[n] = bb1[j];
        for (int k = 0; k < 38; ++k) {
            float w = B1[k * 125 + j];
            const float4* hp = (const float4*)&sIN[k * MN];
            float4 h0 = hp[0], h1 = hp[1], h2 = hp[2], h3 = hp[3];
            acc[0]+=h0.x*w; acc[1]+=h0.y*w; acc[2]+=h0.z*w; acc[3]+=h0.w*w;
            acc[4]+=h1.x*w; acc[5]+=h1.y*w; acc[6]+=h1.z*w; acc[7]+=h1.w*w;
            acc[8]+=h2.x*w; acc[9]+=h2.y*w; acc[10]+=h2.z*w; acc[11]+=h2.w*w;
            acc[12]+=h3.x*w; acc[13]+=h3.y*w; acc[14]+=h3.z*w; acc[15]+=h3.w*w;
        }
        #pragma unroll
        for (int n = 0; n < MN; ++n) sA[j * MN + n] = lrelu(acc[n]);
    }
    __syncthreads();
    // nn3 L2: 125 -> 125
    if (tid < 125) {
        int j = tid;
        float acc[MN];
        #pragma unroll
        for (int n = 0; n < MN; ++n) acc[n] = bb2[j];
        for (int k = 0; k < 125; ++k) {
            float w = B2[k * 125 + j];
            const float4* hp = (const float4*)&sA[k * MN];
            float4 h0 = hp[0], h1 = hp[1], h2 = hp[2], h3 = hp[3];
            acc[0]+=h0.x*w; acc[1]+=h0.y*w; acc[2]+=h0.z*w; acc[3]+=h0.w*w;
            acc[4]+=h1.x*w; acc[5]+=h1.y*w; acc[6]+=h1.z*w; acc[7]+=h1.w*w;
            acc[8]+=h2.x*w; acc[9]+=h2.y*w; acc[10]+=h2.z*w; acc[11]+=h2.w*w;
            acc[12]+=h3.x*w; acc[13]+=h3.y*w; acc[14]+=h3.z*w; acc[15]+=h3.w*w;
        }
        #pragma unroll
        for (int n = 0; n < MN; ++n) sB[j * MN + n] = lrelu(acc[n]);
    }
    __syncthreads();
    // nn3 L3: 125 -> 6 (p4)
    if (tid < 6) {
        int j = tid;
        float acc[MN];
        #pragma unroll
        for (int n = 0; n < MN; ++n) acc[n] = bb3[j];
        for (int k = 0; k < 125; ++k) {
            float w = B3[k * 6 + j];
            const float4* hp = (const float4*)&sB[k * MN];
            float4 h0 = hp[0], h1 = hp[1], h2 = hp[2], h3 = hp[3];
            acc[0]+=h0.x*w; acc[1]+=h0.y*w; acc[2]+=h0.z*w; acc[3]+=h0.w*w;
            acc[4]+=h1.x*w; acc[5]+=h1.y*w; acc[6]+=h1.z*w; acc[7]+=h1.w*w;
            acc[8]+=h2.x*w; acc[9]+=h2.y*w; acc[10]+=h2.z*w; acc[11]+=h2.w*w;
            acc[12]+=h3.x*w; acc[13]+=h3.y*w; acc[14]+=h3.z*w; acc[15]+=h3.w*w;
        }
        for (int n = 0; n < nmax; ++n) out_p4[(n0 + n) * 6 + j] = acc[n];
    }
}

// =================== passthrough (float4) ==========================================
__global__ __launch_bounds__(256) void copy_kernel(
    const float4* __restrict__ a, const float4* __restrict__ b, float4* __restrict__ out) {
    int t = blockIdx.x * blockDim.x + threadIdx.x;
    if (t < 7500) out[15000 + t] = a[t];
    else if (t < 15000) out[15000 + t] = b[t - 7500];
}

static inline int cdiv(int a, int b) { return (a + b - 1) / b; }

extern "C" void kernel_launch(void* const* d_in, const int* in_sizes, int n_in,
                              void* d_out, int out_size, void* d_ws, size_t ws_size,
                              hipStream_t stream) {
    const float* x        = (const float*)d_in[0];
    const float* ygen_id  = (const float*)d_in[1];
    const float* ygen     = (const float*)d_in[2];
    const float* codebook = (const float*)d_in[3];
    const float* nn1_W1 = (const float*)d_in[4];  const float* nn1_b1 = (const float*)d_in[5];
    const float* nn1_W2 = (const float*)d_in[6];  const float* nn1_b2 = (const float*)d_in[7];
    const float* nn1_W3 = (const float*)d_in[8];  const float* nn1_b3 = (const float*)d_in[9];
    const float* gcn_W  = (const float*)d_in[10]; const float* gcn_b  = (const float*)d_in[11];
    const float* gc_Wrel = (const float*)d_in[12]; const float* gc_brel = (const float*)d_in[13];
    const float* gc_Wroot = (const float*)d_in[14];
    const float* nn2_W1 = (const float*)d_in[15]; const float* nn2_b1 = (const float*)d_in[16];
    const float* nn2_W2 = (const float*)d_in[17]; const float* nn2_b2 = (const float*)d_in[18];
    const float* nn2_W3 = (const float*)d_in[19]; const float* nn2_b3 = (const float*)d_in[20];
    const float* nn3_W1 = (const float*)d_in[21]; const float* nn3_b1 = (const float*)d_in[22];
    const float* nn3_W2 = (const float*)d_in[23]; const float* nn3_b2 = (const float*)d_in[24];
    const float* nn3_W3 = (const float*)d_in[25]; const float* nn3_b3 = (const float*)d_in[26];

    float* out = (float*)d_out;
    float* ws  = (float*)d_ws;

    float* h       = ws + 0;        // 60000   (5000x12, pre-leaky)
    float* gc_out  = ws + 60000;    // 160000  (5000x32)
    int*   bin_idx = (int*)(ws + 220000);  // 5000
    int*   order   = (int*)(ws + 225000);  // 5000
    int*   counts  = (int*)(ws + 230000);  // 50

    hipMemsetAsync(counts, 0, NBINS * sizeof(int), stream);

    nn1_kernel<<<cdiv(NN, MN), 128, 0, stream>>>(
        x, nn1_W1, nn1_b1, nn1_W2, nn1_b2, nn1_W3, nn1_b3, codebook,
        h, bin_idx, counts);

    scatter_kernel<<<NBINS, 64, 0, stream>>>(bin_idx, counts, order);

    graph_kernel<<<NBINS, 256, 0, stream>>>(
        h, order, gcn_W, gcn_b, gc_Wrel, gc_brel, gc_Wroot, gc_out);

    nn23_kernel<<<cdiv(NN, MN), 128, 0, stream>>>(
        gc_out,
        nn2_W1, nn2_b1, nn2_W2, nn2_b2, nn2_W3, nn2_b3,
        nn3_W1, nn3_b1, nn3_W2, nn3_b2, nn3_W3, nn3_b3,
        out, out + 30000);

    copy_kernel<<<cdiv(15000, 256), 256, 0, stream>>>(
        (const float4*)ygen_id, (const float4*)ygen, (float4*)out);
}

// Round 5
// 303.771 us; speedup vs baseline: 2.8431x; 1.0692x over previous
//
#include <hip/hip_runtime.h>
#include <math.h>

#define NN 5000
#define NBINS 50
#define BINSZ 100
#define KNN 16
#define BPAD 104          // padded M row length (halves); 208 B stride, 16B aligned
#define MROWS 112         // padded row count in conv kernel (branchless 7-row blocking)
#define MN 8              // nodes per block in MLP kernels

typedef _Float16 half8 __attribute__((ext_vector_type(8)));

__device__ __forceinline__ float lrelu(float x){ return x >= 0.f ? x : 0.01f*x; }

// =================== fused MLP1 + LSH bin: x[5000,12] -> 125 -> 125 -> 12 ===========
__global__ __launch_bounds__(128) void nn1_kernel(
    const float* __restrict__ x,
    const float* __restrict__ W1, const float* __restrict__ b1,
    const float* __restrict__ W2, const float* __restrict__ b2,
    const float* __restrict__ W3, const float* __restrict__ b3,
    const float* __restrict__ cb,
    float* __restrict__ h_out, int* __restrict__ bin_idx) {
    __shared__ float sA[125 * MN];
    __shared__ float sB[125 * MN];
    int tid = threadIdx.x;
    int n0 = blockIdx.x * MN;          // 625 blocks * 8 = 5000 exactly

    if (tid < 12 * MN) {               // x transposed: sA[k][n]
        int k = tid >> 3, n = tid & 7;
        sA[k * MN + n] = x[(n0 + n) * 12 + k];
    }
    __syncthreads();
    // L1: 12 -> 125, leaky  (sA -> sB)
    if (tid < 125) {
        int j = tid;
        float acc[MN];
        #pragma unroll
        for (int n = 0; n < MN; ++n) acc[n] = b1[j];
        #pragma unroll
        for (int k = 0; k < 12; ++k) {
            float w = W1[k * 125 + j];
            const float4* hp = (const float4*)&sA[k * MN];
            float4 h0 = hp[0], h1 = hp[1];
            acc[0]+=h0.x*w; acc[1]+=h0.y*w; acc[2]+=h0.z*w; acc[3]+=h0.w*w;
            acc[4]+=h1.x*w; acc[5]+=h1.y*w; acc[6]+=h1.z*w; acc[7]+=h1.w*w;
        }
        #pragma unroll
        for (int n = 0; n < MN; ++n) sB[j * MN + n] = lrelu(acc[n]);
    }
    __syncthreads();
    // L2: 125 -> 125, leaky (sB -> sA)
    if (tid < 125) {
        int j = tid;
        float acc[MN];
        #pragma unroll
        for (int n = 0; n < MN; ++n) acc[n] = b2[j];
        #pragma unroll 4
        for (int k = 0; k < 125; ++k) {
            float w = W2[k * 125 + j];
            const float4* hp = (const float4*)&sB[k * MN];
            float4 h0 = hp[0], h1 = hp[1];
            acc[0]+=h0.x*w; acc[1]+=h0.y*w; acc[2]+=h0.z*w; acc[3]+=h0.w*w;
            acc[4]+=h1.x*w; acc[5]+=h1.y*w; acc[6]+=h1.z*w; acc[7]+=h1.w*w;
        }
        #pragma unroll
        for (int n = 0; n < MN; ++n) sA[j * MN + n] = lrelu(acc[n]);
    }
    __syncthreads();
    // L3: 125 -> 12 (sA -> global h + stash into sB rows 0..11 for binning)
    if (tid < 12) {
        int j = tid;
        float acc[MN];
        #pragma unroll
        for (int n = 0; n < MN; ++n) acc[n] = b3[j];
        #pragma unroll 4
        for (int k = 0; k < 125; ++k) {
            float w = W3[k * 12 + j];
            const float4* hp = (const float4*)&sA[k * MN];
            float4 h0 = hp[0], h1 = hp[1];
            acc[0]+=h0.x*w; acc[1]+=h0.y*w; acc[2]+=h0.z*w; acc[3]+=h0.w*w;
            acc[4]+=h1.x*w; acc[5]+=h1.y*w; acc[6]+=h1.z*w; acc[7]+=h1.w*w;
        }
        #pragma unroll
        for (int n = 0; n < MN; ++n) {
            h_out[(n0 + n) * 12 + j] = acc[n];
            sB[j * MN + n] = acc[n];
        }
    }
    __syncthreads();
    // LSH bin per node (argmax over [mul, -mul], first max wins)
    if (tid < MN) {
        int n = tid;
        float hv[12];
        #pragma unroll
        for (int k = 0; k < 12; ++k) hv[k] = sB[k * MN + n];
        float best = -INFINITY; int bi = 0;
        for (int c = 0; c < 25; ++c) {
            float m = 0.f;
            #pragma unroll
            for (int k = 0; k < 12; ++k) m += hv[k] * cb[k * 100 + c];  // codebook [12,100]
            if (m > best) { best = m; bi = c; }
        }
        for (int c = 0; c < 25; ++c) {
            float m = 0.f;
            #pragma unroll
            for (int k = 0; k < 12; ++k) m += hv[k] * cb[k * 100 + c];
            if (-m > best) { best = -m; bi = c + 25; }
        }
        bin_idx[n0 + n] = bi;
    }
}

// =================== stable argsort-by-bin, self-contained (no counts array) ========
__global__ __launch_bounds__(64) void scatter_kernel(
    const int* __restrict__ bin_idx, int* __restrict__ order) {
    int b = blockIdx.x, lane = threadIdx.x;
    unsigned long long below = (lane == 0) ? 0ULL : ((~0ULL) >> (64 - lane));
    int cnt_lt = 0;
    for (int base = 0; base < NN; base += 64) {
        int i = base + lane;
        int bi = (i < NN) ? bin_idx[i] : 999;
        cnt_lt += __popcll(__ballot(bi < b));
    }
    int offs = cnt_lt;
    for (int base = 0; base < NN; base += 64) {
        int i = base + lane;
        int bi = (i < NN) ? bin_idx[i] : 999;
        unsigned long long m = __ballot(bi == b);
        if (bi == b) order[offs + __popcll(m & below)] = i;
        offs += __popcll(m);
    }
}

// =================== K1: build dense fp16 edge matrix M + dis (50 blocks) ===========
// 2-way-split top-16 per row: 200 threads do 50-candidate local top16; 100 merge.
__global__ __launch_bounds__(256) void build_kernel(
    const float* __restrict__ h, const int* __restrict__ order,
    _Float16* __restrict__ Mg, float* __restrict__ dis_g) {
    __shared__ _Float16 M[BINSZ * BPAD];     // 20800 B
    __shared__ float s_h[BINSZ * 12];
    __shared__ int   s_nodes[BINSZ];
    __shared__ float s_tv[200 * KNN];        // 12.8 KB
    __shared__ int   s_tix[200 * KNN];       // 12.8 KB
    int p = blockIdx.x, tid = threadIdx.x;

    if (tid < BINSZ) s_nodes[tid] = order[p * BINSZ + tid];
    for (int t = tid; t < BINSZ * BPAD / 2; t += 256) ((int*)M)[t] = 0;
    __syncthreads();
    for (int t = tid; t < BINSZ * 12; t += 256) {
        int i = t / 12, k = t - i * 12;
        s_h[t] = h[s_nodes[i] * 12 + k];
    }
    __syncthreads();

    // local top-16 over 50 candidates (row = tid>>1, half = tid&1)
    if (tid < 200) {
        int row = tid >> 1, half = tid & 1;
        const float4* xp = (const float4*)&s_h[row * 12];
        float4 x0 = xp[0], x1 = xp[1], x2 = xp[2];
        float tv[KNN]; int ti[KNN];
        #pragma unroll
        for (int k = 0; k < KNN; ++k) { tv[k] = -1e30f; ti[k] = 0; }
        int j0 = half * 50;
        for (int jj = 0; jj < 50; ++jj) {
            int j = j0 + jj;
            const float4* ap = (const float4*)&s_h[j * 12];
            float4 a0 = ap[0], a1 = ap[1], a2 = ap[2];
            float d = x0.x*a0.x + x0.y*a0.y + x0.z*a0.z + x0.w*a0.w
                    + x1.x*a1.x + x1.y*a1.y + x1.z*a1.z + x1.w*a1.w
                    + x2.x*a2.x + x2.y*a2.y + x2.z*a2.z + x2.w*a2.w;
            float v = 1.f / (1.f + expf(-d));
            if (v > tv[KNN - 1]) {
                int vi = j;
                #pragma unroll
                for (int k = 0; k < KNN; ++k) {
                    bool gt = v > tv[k];            // strict: lower j stays ahead
                    float nv = gt ? v : tv[k];  int ni = gt ? vi : ti[k];
                    float ov = gt ? tv[k] : v;  int oi = gt ? ti[k] : vi;
                    tv[k] = nv; ti[k] = ni; v = ov; vi = oi;
                }
            }
        }
        #pragma unroll
        for (int k = 0; k < KNN; ++k) {
            s_tv[tid * KNN + k] = tv[k];
            s_tix[tid * KNN + k] = ti[k];
        }
    }
    __syncthreads();

    // stable merge of the two sorted 16-lists (A: j<50, B: j>=50; ties -> A)
    if (tid < BINSZ) {
        int base = tid * 32;
        int ia = 0, ib = 0;
        #pragma unroll
        for (int k = 0; k < KNN; ++k) {
            float av = s_tv[base + ia], bv = s_tv[base + 16 + ib];
            bool tA = av >= bv;
            float v = tA ? av : bv;
            int ix = tA ? s_tix[base + ia] : s_tix[base + 16 + ib];
            ia += tA; ib += !tA;
            M[ix * BPAD + tid] = (_Float16)v;    // edge tid -> ix
        }
    }
    __syncthreads();

    // write M to global + rowsum -> dis
    for (int t = tid; t < BINSZ * BPAD / 8; t += 256)
        ((uint4*)(Mg + (size_t)p * BINSZ * BPAD))[t] = ((const uint4*)M)[t];
    if (tid < BINSZ) {
        float dsum = 1.0f;   // self-loop
        #pragma unroll 13
        for (int sc = 0; sc < 13; ++sc) {
            half8 m = *(const half8*)&M[tid * BPAD + sc * 8];
            dsum += (float)m[0] + (float)m[1] + (float)m[2] + (float)m[3]
                  + (float)m[4] + (float)m[5] + (float)m[6] + (float)m[7];
        }
        dis_g[p * BINSZ + tid] = 1.0f / sqrtf(dsum);
    }
}

// =================== K2: channel-sliced convs (50 chunks x 4 groups = 200 blocks) ===
// group handles 8 channels: hWd -> gcn = GCN(M) -> agg = M*gcn; scatter to node order.
__global__ __launch_bounds__(128) void conv_kernel(
    const _Float16* __restrict__ Mg, const float* __restrict__ dis_g,
    const float* __restrict__ h, const int* __restrict__ order,
    const float* __restrict__ gcn_W, const float* __restrict__ gcn_b,
    float* __restrict__ gcn_n, float* __restrict__ agg_n) {
    __shared__ _Float16 M[MROWS * BPAD];     // 23296 B (rows 100..111 zero)
    __shared__ float s_h[BINSZ * 12];
    __shared__ int   s_nodes[BINSZ];
    __shared__ float s_dis[BINSZ];
    __shared__ float s_w[12 * 8];
    __shared__ float s_hWd[8 * BPAD];        // [cc][s], transposed
    __shared__ float s_gcn[8 * BPAD];
    int bid = blockIdx.x, tid = threadIdx.x;
    int p = bid >> 2, cg = bid & 3, c0 = cg * 8;

    if (tid < BINSZ) {
        s_nodes[tid] = order[p * BINSZ + tid];
        s_dis[tid]   = dis_g[p * BINSZ + tid];
    }
    for (int t = tid; t < 96; t += 128)
        s_w[t] = gcn_W[(t >> 3) * 32 + c0 + (t & 7)];
    for (int t = tid; t < BINSZ * BPAD / 8; t += 128)
        ((uint4*)M)[t] = ((const uint4*)(Mg + (size_t)p * BINSZ * BPAD))[t];
    for (int t = tid; t < (MROWS - BINSZ) * BPAD / 2; t += 128)
        ((int*)(M + BINSZ * BPAD))[t] = 0;
    // zero hWd/gcn pad cols 100..103
    if (tid < 32) {
        s_hWd[(tid >> 2) * BPAD + 100 + (tid & 3)] = 0.f;
        s_gcn[(tid >> 2) * BPAD + 100 + (tid & 3)] = 0.f;
    }
    __syncthreads();
    for (int t = tid; t < BINSZ * 12; t += 128) {
        int i = t / 12, k = t - i * 12;
        s_h[t] = h[s_nodes[i] * 12 + k];
    }
    __syncthreads();

    // hWd[cc][s] = dis[s] * (leaky(h[s]) @ W[:,c0+cc])
    for (int o = tid; o < BINSZ * 8; o += 128) {
        int s = o >> 3, cc = o & 7;
        float a = 0.f;
        #pragma unroll
        for (int k = 0; k < 12; ++k) a += lrelu(s_h[s * 12 + k]) * s_w[k * 8 + cc];
        s_hWd[cc * BPAD + s] = s_dis[s] * a;
    }
    __syncthreads();

    int cc = tid & 7, dg = tid >> 3;   // dg in [0,16)
    // mm1: gcn[d][cc] = dis[d]*(sum_s M[d][s]*hWd[cc][s] + hWd[cc][d]) + b
    {
        float acc[7];
        #pragma unroll
        for (int r = 0; r < 7; ++r) acc[r] = 0.f;
        for (int sc = 0; sc < 13; ++sc) {
            float4 hv0 = *(const float4*)&s_hWd[cc * BPAD + sc * 8];
            float4 hv1 = *(const float4*)&s_hWd[cc * BPAD + sc * 8 + 4];
            #pragma unroll
            for (int r = 0; r < 7; ++r) {
                int d = dg + 16 * r;
                half8 m = *(const half8*)&M[d * BPAD + sc * 8];
                acc[r] += (float)m[0]*hv0.x + (float)m[1]*hv0.y + (float)m[2]*hv0.z + (float)m[3]*hv0.w
                        + (float)m[4]*hv1.x + (float)m[5]*hv1.y + (float)m[6]*hv1.z + (float)m[7]*hv1.w;
            }
        }
        float bc = gcn_b[c0 + cc];
        #pragma unroll
        for (int r = 0; r < 7; ++r) {
            int d = dg + 16 * r;
            if (d < BINSZ) {
                float g = s_dis[d] * (acc[r] + s_hWd[cc * BPAD + d]) + bc;
                s_gcn[cc * BPAD + d] = g;
                gcn_n[s_nodes[d] * 32 + c0 + cc] = g;
            }
        }
    }
    __syncthreads();
    // mm2: agg[d][cc] = sum_s M[d][s]*gcn[cc][s]
    {
        float acc[7];
        #pragma unroll
        for (int r = 0; r < 7; ++r) acc[r] = 0.f;
        for (int sc = 0; sc < 13; ++sc) {
            float4 hv0 = *(const float4*)&s_gcn[cc * BPAD + sc * 8];
            float4 hv1 = *(const float4*)&s_gcn[cc * BPAD + sc * 8 + 4];
            #pragma unroll
            for (int r = 0; r < 7; ++r) {
                int d = dg + 16 * r;
                half8 m = *(const half8*)&M[d * BPAD + sc * 8];
                acc[r] += (float)m[0]*hv0.x + (float)m[1]*hv0.y + (float)m[2]*hv0.z + (float)m[3]*hv0.w
                        + (float)m[4]*hv1.x + (float)m[5]*hv1.y + (float)m[6]*hv1.z + (float)m[7]*hv1.w;
            }
        }
        #pragma unroll
        for (int r = 0; r < 7; ++r) {
            int d = dg + 16 * r;
            if (d < BINSZ) agg_n[s_nodes[d] * 32 + c0 + cc] = acc[r];
        }
    }
}

// =================== fused combine + nn2 + nn3 ======================================
__global__ __launch_bounds__(128) void nn23_kernel(
    const float* __restrict__ gcn_n, const float* __restrict__ agg_n,
    const float* __restrict__ Wrel, const float* __restrict__ brel,
    const float* __restrict__ Wroot,
    const float* __restrict__ A1, const float* __restrict__ ab1,
    const float* __restrict__ A2, const float* __restrict__ ab2,
    const float* __restrict__ A3, const float* __restrict__ ab3,
    const float* __restrict__ B1, const float* __restrict__ bb1,
    const float* __restrict__ B2, const float* __restrict__ bb2,
    const float* __restrict__ B3, const float* __restrict__ bb3,
    float* __restrict__ out_ids, float* __restrict__ out_p4) {
    __shared__ float s_ag[MN * 32];
    __shared__ float s_gc[MN * 32];
    __shared__ float sIN[38 * MN];     // [k][n]; rows 32..37 = ids
    __shared__ float sA[125 * MN];
    __shared__ float sB[125 * MN];
    int tid = threadIdx.x;
    int n0 = blockIdx.x * MN;

    for (int t = tid; t < MN * 32; t += 128) {
        s_ag[t] = agg_n[n0 * 32 + t];
        s_gc[t] = gcn_n[n0 * 32 + t];
    }
    __syncthreads();
    // combine: gc[n][j] = leaky(agg@Wrel + brel + gcn@Wroot)  -> sIN[j][n]
    for (int o = tid; o < 32 * MN; o += 128) {
        int j = o >> 3, n = o & 7;
        float acc = brel[j];
        #pragma unroll 8
        for (int k = 0; k < 32; ++k)
            acc += s_ag[n * 32 + k] * Wrel[k * 32 + j] + s_gc[n * 32 + k] * Wroot[k * 32 + j];
        sIN[j * MN + n] = lrelu(acc);
    }
    __syncthreads();
    // nn2 L1: 32 -> 125
    if (tid < 125) {
        int j = tid;
        float acc[MN];
        #pragma unroll
        for (int n = 0; n < MN; ++n) acc[n] = ab1[j];
        #pragma unroll 4
        for (int k = 0; k < 32; ++k) {
            float w = A1[k * 125 + j];
            const float4* hp = (const float4*)&sIN[k * MN];
            float4 h0 = hp[0], h1 = hp[1];
            acc[0]+=h0.x*w; acc[1]+=h0.y*w; acc[2]+=h0.z*w; acc[3]+=h0.w*w;
            acc[4]+=h1.x*w; acc[5]+=h1.y*w; acc[6]+=h1.z*w; acc[7]+=h1.w*w;
        }
        #pragma unroll
        for (int n = 0; n < MN; ++n) sA[j * MN + n] = lrelu(acc[n]);
    }
    __syncthreads();
    // nn2 L2: 125 -> 125
    if (tid < 125) {
        int j = tid;
        float acc[MN];
        #pragma unroll
        for (int n = 0; n < MN; ++n) acc[n] = ab2[j];
        #pragma unroll 4
        for (int k = 0; k < 125; ++k) {
            float w = A2[k * 125 + j];
            const float4* hp = (const float4*)&sA[k * MN];
            float4 h0 = hp[0], h1 = hp[1];
            acc[0]+=h0.x*w; acc[1]+=h0.y*w; acc[2]+=h0.z*w; acc[3]+=h0.w*w;
            acc[4]+=h1.x*w; acc[5]+=h1.y*w; acc[6]+=h1.z*w; acc[7]+=h1.w*w;
        }
        #pragma unroll
        for (int n = 0; n < MN; ++n) sB[j * MN + n] = lrelu(acc[n]);
    }
    __syncthreads();
    // nn2 L3: 125 -> 6 (ids) -> out + sIN rows 32..37
    if (tid < 6) {
        int j = tid;
        float acc[MN];
        #pragma unroll
        for (int n = 0; n < MN; ++n) acc[n] = ab3[j];
        #pragma unroll 4
        for (int k = 0; k < 125; ++k) {
            float w = A3[k * 6 + j];
            const float4* hp = (const float4*)&sB[k * MN];
            float4 h0 = hp[0], h1 = hp[1];
            acc[0]+=h0.x*w; acc[1]+=h0.y*w; acc[2]+=h0.z*w; acc[3]+=h0.w*w;
            acc[4]+=h1.x*w; acc[5]+=h1.y*w; acc[6]+=h1.z*w; acc[7]+=h1.w*w;
        }
        #pragma unroll
        for (int n = 0; n < MN; ++n) {
            out_ids[(n0 + n) * 6 + j] = acc[n];
            sIN[(32 + j) * MN + n] = acc[n];
        }
    }
    __syncthreads();
    // nn3 L1: 38 -> 125
    if (tid < 125) {
        int j = tid;
        float acc[MN];
        #pragma unroll
        for (int n = 0; n < MN; ++n) acc[n] = bb1[j];
        #pragma unroll 2
        for (int k = 0; k < 38; ++k) {
            float w = B1[k * 125 + j];
            const float4* hp = (const float4*)&sIN[k * MN];
            float4 h0 = hp[0], h1 = hp[1];
            acc[0]+=h0.x*w; acc[1]+=h0.y*w; acc[2]+=h0.z*w; acc[3]+=h0.w*w;
            acc[4]+=h1.x*w; acc[5]+=h1.y*w; acc[6]+=h1.z*w; acc[7]+=h1.w*w;
        }
        #pragma unroll
        for (int n = 0; n < MN; ++n) sA[j * MN + n] = lrelu(acc[n]);
    }
    __syncthreads();
    // nn3 L2: 125 -> 125
    if (tid < 125) {
        int j = tid;
        float acc[MN];
        #pragma unroll
        for (int n = 0; n < MN; ++n) acc[n] = bb2[j];
        #pragma unroll 4
        for (int k = 0; k < 125; ++k) {
            float w = B2[k * 125 + j];
            const float4* hp = (const float4*)&sA[k * MN];
            float4 h0 = hp[0], h1 = hp[1];
            acc[0]+=h0.x*w; acc[1]+=h0.y*w; acc[2]+=h0.z*w; acc[3]+=h0.w*w;
            acc[4]+=h1.x*w; acc[5]+=h1.y*w; acc[6]+=h1.z*w; acc[7]+=h1.w*w;
        }
        #pragma unroll
        for (int n = 0; n < MN; ++n) sB[j * MN + n] = lrelu(acc[n]);
    }
    __syncthreads();
    // nn3 L3: 125 -> 6 (p4)
    if (tid < 6) {
        int j = tid;
        float acc[MN];
        #pragma unroll
        for (int n = 0; n < MN; ++n) acc[n] = bb3[j];
        #pragma unroll 4
        for (int k = 0; k < 125; ++k) {
            float w = B3[k * 6 + j];
            const float4* hp = (const float4*)&sB[k * MN];
            float4 h0 = hp[0], h1 = hp[1];
            acc[0]+=h0.x*w; acc[1]+=h0.y*w; acc[2]+=h0.z*w; acc[3]+=h0.w*w;
            acc[4]+=h1.x*w; acc[5]+=h1.y*w; acc[6]+=h1.z*w; acc[7]+=h1.w*w;
        }
        #pragma unroll
        for (int n = 0; n < MN; ++n) out_p4[(n0 + n) * 6 + j] = acc[n];
    }
}

// =================== passthrough (float4) ==========================================
__global__ __launch_bounds__(256) void copy_kernel(
    const float4* __restrict__ a, const float4* __restrict__ b, float4* __restrict__ out) {
    int t = blockIdx.x * blockDim.x + threadIdx.x;
    if (t < 7500) out[15000 + t] = a[t];
    else if (t < 15000) out[15000 + t] = b[t - 7500];
}

static inline int cdiv(int a, int b) { return (a + b - 1) / b; }

extern "C" void kernel_launch(void* const* d_in, const int* in_sizes, int n_in,
                              void* d_out, int out_size, void* d_ws, size_t ws_size,
                              hipStream_t stream) {
    const float* x        = (const float*)d_in[0];
    const float* ygen_id  = (const float*)d_in[1];
    const float* ygen     = (const float*)d_in[2];
    const float* codebook = (const float*)d_in[3];
    const float* nn1_W1 = (const float*)d_in[4];  const float* nn1_b1 = (const float*)d_in[5];
    const float* nn1_W2 = (const float*)d_in[6];  const float* nn1_b2 = (const float*)d_in[7];
    const float* nn1_W3 = (const float*)d_in[8];  const float* nn1_b3 = (const float*)d_in[9];
    const float* gcn_W  = (const float*)d_in[10]; const float* gcn_b  = (const float*)d_in[11];
    const float* gc_Wrel = (const float*)d_in[12]; const float* gc_brel = (const float*)d_in[13];
    const float* gc_Wroot = (const float*)d_in[14];
    const float* nn2_W1 = (const float*)d_in[15]; const float* nn2_b1 = (const float*)d_in[16];
    const float* nn2_W2 = (const float*)d_in[17]; const float* nn2_b2 = (const float*)d_in[18];
    const float* nn2_W3 = (const float*)d_in[19]; const float* nn2_b3 = (const float*)d_in[20];
    const float* nn3_W1 = (const float*)d_in[21]; const float* nn3_b1 = (const float*)d_in[22];
    const float* nn3_W2 = (const float*)d_in[23]; const float* nn3_b2 = (const float*)d_in[24];
    const float* nn3_W3 = (const float*)d_in[25]; const float* nn3_b3 = (const float*)d_in[26];

    float* out = (float*)d_out;
    float* ws  = (float*)d_ws;

    // workspace layout (float offsets)
    float* h      = ws + 0;         // 60000   (5000x12)
    float* gcn_n  = ws + 60000;     // 160000  (5000x32, node order)
    float* agg_n  = ws + 220000;    // 160000
    float* dis_g  = ws + 380000;    // 5000
    _Float16* Mg  = (_Float16*)(ws + 385000);   // 50*100*104 halves = 260000 floats
    int* bin_idx  = (int*)(ws + 645000);        // 5000
    int* order    = (int*)(ws + 650000);        // 5000

    nn1_kernel<<<NN / MN, 128, 0, stream>>>(
        x, nn1_W1, nn1_b1, nn1_W2, nn1_b2, nn1_W3, nn1_b3, codebook,
        h, bin_idx);

    scatter_kernel<<<NBINS, 64, 0, stream>>>(bin_idx, order);

    build_kernel<<<NBINS, 256, 0, stream>>>(h, order, Mg, dis_g);

    conv_kernel<<<NBINS * 4, 128, 0, stream>>>(
        Mg, dis_g, h, order, gcn_W, gcn_b, gcn_n, agg_n);

    nn23_kernel<<<NN / MN, 128, 0, stream>>>(
        gcn_n, agg_n, gc_Wrel, gc_brel, gc_Wroot,
        nn2_W1, nn2_b1, nn2_W2, nn2_b2, nn2_W3, nn2_b3,
        nn3_W1, nn3_b1, nn3_W2, nn3_b2, nn3_W3, nn3_b3,
        out, out + 30000);

    copy_kernel<<<cdiv(15000, 256), 256, 0, stream>>>(
        (const float4*)ygen_id, (const float4*)ygen, (float4*)out);
}

// Round 6
// 251.230 us; speedup vs baseline: 3.4377x; 1.2091x over previous
//
#include <hip/hip_runtime.h>
#include <math.h>

#define NN 5000
#define NBINS 50
#define BINSZ 100
#define KNN 16
#define BPAD 104          // padded M row length (halves); 208 B stride, 16B aligned
#define MROWS 112         // padded row count in conv kernel (branchless 7-row blocking)
#define MN 8              // nodes per block in MLP kernels

typedef _Float16 half8 __attribute__((ext_vector_type(8)));

__device__ __forceinline__ float lrelu(float x){ return x >= 0.f ? x : 0.01f*x; }

// =================== fused MLP1 + LSH bin: x[5000,12] -> 125 -> 125 -> 12 ===========
// All weights staged through LDS (chunked), conflict-free stride-1 ds_read.
__global__ __launch_bounds__(128) void nn1_kernel(
    const float* __restrict__ x,
    const float* __restrict__ W1, const float* __restrict__ b1,
    const float* __restrict__ W2, const float* __restrict__ b2,
    const float* __restrict__ W3, const float* __restrict__ b3,
    const float* __restrict__ cb,
    float* __restrict__ h_out, int* __restrict__ bin_idx) {
    __shared__ float sW[8000];        // 32 KB weight stage (max chunk 64x125)
    __shared__ float sA[125 * MN];    // activations [k][n]
    __shared__ float sB[125 * MN];
    __shared__ float sCB[12 * 25];    // codebook cols 0..24, [k][c]
    int tid = threadIdx.x;
    int n0 = blockIdx.x * MN;         // 625 blocks * 8 = 5000

    // stage x transposed + codebook + W1
    if (tid < 96) { int k = tid >> 3, n = tid & 7; sA[k * MN + n] = x[(n0 + n) * 12 + k]; }
    for (int t = tid; t < 300; t += 128) { int k = t / 25, c = t - k * 25; sCB[t] = cb[k * 100 + c]; }
    for (int t = tid; t < 375; t += 128) ((float4*)sW)[t] = ((const float4*)W1)[t];  // 1500 floats
    __syncthreads();
    // L1: 12 -> 125, leaky  (sA -> sB)
    float acc[MN];
    if (tid < 125) {
        int j = tid;
        #pragma unroll
        for (int n = 0; n < MN; ++n) acc[n] = b1[j];
        #pragma unroll
        for (int k = 0; k < 12; ++k) {
            float w = sW[k * 125 + j];
            const float4* hp = (const float4*)&sA[k * MN];
            float4 h0 = hp[0], h1 = hp[1];
            acc[0]+=h0.x*w; acc[1]+=h0.y*w; acc[2]+=h0.z*w; acc[3]+=h0.w*w;
            acc[4]+=h1.x*w; acc[5]+=h1.y*w; acc[6]+=h1.z*w; acc[7]+=h1.w*w;
        }
        #pragma unroll
        for (int n = 0; n < MN; ++n) sB[tid * MN + n] = lrelu(acc[n]);
    }
    __syncthreads();
    // L2: 125 -> 125, leaky (sB -> sA), W2 staged in 2 chunks (64 + 61 rows)
    for (int t = tid; t < 2000; t += 128) ((float4*)sW)[t] = ((const float4*)W2)[t];   // rows 0..63
    __syncthreads();
    if (tid < 125) {
        int j = tid;
        #pragma unroll
        for (int n = 0; n < MN; ++n) acc[n] = b2[j];
        #pragma unroll 4
        for (int k = 0; k < 64; ++k) {
            float w = sW[k * 125 + j];
            const float4* hp = (const float4*)&sB[k * MN];
            float4 h0 = hp[0], h1 = hp[1];
            acc[0]+=h0.x*w; acc[1]+=h0.y*w; acc[2]+=h0.z*w; acc[3]+=h0.w*w;
            acc[4]+=h1.x*w; acc[5]+=h1.y*w; acc[6]+=h1.z*w; acc[7]+=h1.w*w;
        }
    }
    __syncthreads();
    for (int t = tid; t < 1906; t += 128) ((float4*)sW)[t] = ((const float4*)(W2 + 8000))[t];  // rows 64..124
    if (tid == 0) sW[7624] = W2[8000 + 7624];
    __syncthreads();
    if (tid < 125) {
        int j = tid;
        #pragma unroll 4
        for (int k = 0; k < 61; ++k) {
            float w = sW[k * 125 + j];
            const float4* hp = (const float4*)&sB[(64 + k) * MN];
            float4 h0 = hp[0], h1 = hp[1];
            acc[0]+=h0.x*w; acc[1]+=h0.y*w; acc[2]+=h0.z*w; acc[3]+=h0.w*w;
            acc[4]+=h1.x*w; acc[5]+=h1.y*w; acc[6]+=h1.z*w; acc[7]+=h1.w*w;
        }
    }
    __syncthreads();
    if (tid < 125) {
        #pragma unroll
        for (int n = 0; n < MN; ++n) sA[tid * MN + n] = lrelu(acc[n]);
    }
    __syncthreads();
    // L3: 125 -> 12, k-split across two thread groups; W3 (125x12 = 1500 floats)
    for (int t = tid; t < 375; t += 128) ((float4*)sW)[t] = ((const float4*)W3)[t];
    __syncthreads();
    {
        int half = (tid >= 64), j = half ? tid - 64 : tid;
        if (j < 12) {
            int k0 = half ? 63 : 0, k1 = half ? 125 : 63;
            float ps[MN];
            #pragma unroll
            for (int n = 0; n < MN; ++n) ps[n] = 0.f;
            for (int k = k0; k < k1; ++k) {
                float w = sW[k * 12 + j];
                const float4* hp = (const float4*)&sA[k * MN];
                float4 h0 = hp[0], h1 = hp[1];
                ps[0]+=h0.x*w; ps[1]+=h0.y*w; ps[2]+=h0.z*w; ps[3]+=h0.w*w;
                ps[4]+=h1.x*w; ps[5]+=h1.y*w; ps[6]+=h1.z*w; ps[7]+=h1.w*w;
            }
            #pragma unroll
            for (int n = 0; n < MN; ++n) sB[(half * 12 + j) * MN + n] = ps[n];
        }
    }
    __syncthreads();
    if (tid < 12) {
        int j = tid;
        float bj = b3[j];
        #pragma unroll
        for (int n = 0; n < MN; ++n) {
            float v = sB[j * MN + n] + sB[(12 + j) * MN + n] + bj;
            h_out[(n0 + n) * 12 + j] = v;
            sB[(24 + j) * MN + n] = v;
        }
    }
    __syncthreads();
    // LSH bin per node (argmax over [mul, -mul], first max wins)
    if (tid < MN) {
        int n = tid;
        float hv[12];
        #pragma unroll
        for (int k = 0; k < 12; ++k) hv[k] = sB[(24 + k) * MN + n];
        float best = -INFINITY; int bi = 0;
        for (int c = 0; c < 25; ++c) {
            float m = 0.f;
            #pragma unroll
            for (int k = 0; k < 12; ++k) m += hv[k] * sCB[k * 25 + c];
            if (m > best) { best = m; bi = c; }
        }
        for (int c = 0; c < 25; ++c) {
            float m = 0.f;
            #pragma unroll
            for (int k = 0; k < 12; ++k) m += hv[k] * sCB[k * 25 + c];
            if (-m > best) { best = -m; bi = c + 25; }
        }
        bin_idx[n0 + n] = bi;
    }
}

// =================== stable argsort-by-bin (LDS-staged) + ygen passthrough ==========
__global__ __launch_bounds__(64) void scatter_kernel(
    const int* __restrict__ bin_idx, int* __restrict__ order,
    const float4* __restrict__ ygen_id4, const float4* __restrict__ ygen4,
    float4* __restrict__ out4) {
    __shared__ int sBI[NN];
    int b = blockIdx.x, lane = threadIdx.x;
    for (int t = lane; t < NN / 4; t += 64) ((int4*)sBI)[t] = ((const int4*)bin_idx)[t];
    // fold the passthrough copy in (independent work, hides stage latency)
    for (int t = lane; t < 300; t += 64) {
        int g = b * 300 + t;
        out4[15000 + g] = (g < 7500) ? ygen_id4[g] : ygen4[g - 7500];
    }
    __syncthreads();
    unsigned long long below = (lane == 0) ? 0ULL : ((~0ULL) >> (64 - lane));
    int cnt_lt = 0;
    for (int base = 0; base < NN; base += 64) {
        int i = base + lane;
        int bi = (i < NN) ? sBI[i] : 999;
        cnt_lt += __popcll(__ballot(bi < b));
    }
    int offs = cnt_lt;
    for (int base = 0; base < NN; base += 64) {
        int i = base + lane;
        int bi = (i < NN) ? sBI[i] : 999;
        unsigned long long m = __ballot(bi == b);
        if (bi == b) order[offs + __popcll(m & below)] = i;
        offs += __popcll(m);
    }
}

// =================== K1: build dense fp16 edge matrix M + dis (50 blocks) ===========
__global__ __launch_bounds__(256) void build_kernel(
    const float* __restrict__ h, const int* __restrict__ order,
    _Float16* __restrict__ Mg, float* __restrict__ dis_g) {
    __shared__ _Float16 M[BINSZ * BPAD];     // 20800 B
    __shared__ float s_h[BINSZ * 12];
    __shared__ int   s_nodes[BINSZ];
    __shared__ float s_tv[200 * KNN];
    __shared__ int   s_tix[200 * KNN];
    int p = blockIdx.x, tid = threadIdx.x;

    if (tid < BINSZ) s_nodes[tid] = order[p * BINSZ + tid];
    for (int t = tid; t < BINSZ * BPAD / 2; t += 256) ((int*)M)[t] = 0;
    __syncthreads();
    for (int t = tid; t < BINSZ * 12; t += 256) {
        int i = t / 12, k = t - i * 12;
        s_h[t] = h[s_nodes[i] * 12 + k];
    }
    __syncthreads();

    if (tid < 200) {
        int row = tid >> 1, half = tid & 1;
        const float4* xp = (const float4*)&s_h[row * 12];
        float4 x0 = xp[0], x1 = xp[1], x2 = xp[2];
        float tv[KNN]; int ti[KNN];
        #pragma unroll
        for (int k = 0; k < KNN; ++k) { tv[k] = -1e30f; ti[k] = 0; }
        int j0 = half * 50;
        for (int jj = 0; jj < 50; ++jj) {
            int j = j0 + jj;
            const float4* ap = (const float4*)&s_h[j * 12];
            float4 a0 = ap[0], a1 = ap[1], a2 = ap[2];
            float d = x0.x*a0.x + x0.y*a0.y + x0.z*a0.z + x0.w*a0.w
                    + x1.x*a1.x + x1.y*a1.y + x1.z*a1.z + x1.w*a1.w
                    + x2.x*a2.x + x2.y*a2.y + x2.z*a2.z + x2.w*a2.w;
            float v = 1.f / (1.f + expf(-d));
            if (v > tv[KNN - 1]) {
                int vi = j;
                #pragma unroll
                for (int k = 0; k < KNN; ++k) {
                    bool gt = v > tv[k];
                    float nv = gt ? v : tv[k];  int ni = gt ? vi : ti[k];
                    float ov = gt ? tv[k] : v;  int oi = gt ? ti[k] : vi;
                    tv[k] = nv; ti[k] = ni; v = ov; vi = oi;
                }
            }
        }
        #pragma unroll
        for (int k = 0; k < KNN; ++k) {
            s_tv[tid * KNN + k] = tv[k];
            s_tix[tid * KNN + k] = ti[k];
        }
    }
    __syncthreads();

    if (tid < BINSZ) {
        int base = tid * 32;
        int ia = 0, ib = 0;
        #pragma unroll
        for (int k = 0; k < KNN; ++k) {
            float av = s_tv[base + ia], bv = s_tv[base + 16 + ib];
            bool tA = av >= bv;
            float v = tA ? av : bv;
            int ix = tA ? s_tix[base + ia] : s_tix[base + 16 + ib];
            ia += tA; ib += !tA;
            M[ix * BPAD + tid] = (_Float16)v;
        }
    }
    __syncthreads();

    for (int t = tid; t < BINSZ * BPAD / 8; t += 256)
        ((uint4*)(Mg + (size_t)p * BINSZ * BPAD))[t] = ((const uint4*)M)[t];
    if (tid < BINSZ) {
        float dsum = 1.0f;
        #pragma unroll 13
        for (int sc = 0; sc < 13; ++sc) {
            half8 m = *(const half8*)&M[tid * BPAD + sc * 8];
            dsum += (float)m[0] + (float)m[1] + (float)m[2] + (float)m[3]
                  + (float)m[4] + (float)m[5] + (float)m[6] + (float)m[7];
        }
        dis_g[p * BINSZ + tid] = 1.0f / sqrtf(dsum);
    }
}

// =================== K2: channel-sliced convs (200 blocks) ==========================
__global__ __launch_bounds__(128) void conv_kernel(
    const _Float16* __restrict__ Mg, const float* __restrict__ dis_g,
    const float* __restrict__ h, const int* __restrict__ order,
    const float* __restrict__ gcn_W, const float* __restrict__ gcn_b,
    float* __restrict__ gcn_n, float* __restrict__ agg_n) {
    __shared__ _Float16 M[MROWS * BPAD];
    __shared__ float s_h[BINSZ * 12];
    __shared__ int   s_nodes[BINSZ];
    __shared__ float s_dis[BINSZ];
    __shared__ float s_w[12 * 8];
    __shared__ float s_hWd[8 * BPAD];
    __shared__ float s_gcn[8 * BPAD];
    int bid = blockIdx.x, tid = threadIdx.x;
    int p = bid >> 2, cg = bid & 3, c0 = cg * 8;

    if (tid < BINSZ) {
        s_nodes[tid] = order[p * BINSZ + tid];
        s_dis[tid]   = dis_g[p * BINSZ + tid];
    }
    for (int t = tid; t < 96; t += 128)
        s_w[t] = gcn_W[(t >> 3) * 32 + c0 + (t & 7)];
    for (int t = tid; t < BINSZ * BPAD / 8; t += 128)
        ((uint4*)M)[t] = ((const uint4*)(Mg + (size_t)p * BINSZ * BPAD))[t];
    for (int t = tid; t < (MROWS - BINSZ) * BPAD / 2; t += 128)
        ((int*)(M + BINSZ * BPAD))[t] = 0;
    if (tid < 32) {
        s_hWd[(tid >> 2) * BPAD + 100 + (tid & 3)] = 0.f;
        s_gcn[(tid >> 2) * BPAD + 100 + (tid & 3)] = 0.f;
    }
    __syncthreads();
    for (int t = tid; t < BINSZ * 12; t += 128) {
        int i = t / 12, k = t - i * 12;
        s_h[t] = h[s_nodes[i] * 12 + k];
    }
    __syncthreads();

    for (int o = tid; o < BINSZ * 8; o += 128) {
        int s = o >> 3, cc = o & 7;
        float a = 0.f;
        #pragma unroll
        for (int k = 0; k < 12; ++k) a += lrelu(s_h[s * 12 + k]) * s_w[k * 8 + cc];
        s_hWd[cc * BPAD + s] = s_dis[s] * a;
    }
    __syncthreads();

    int cc = tid & 7, dg = tid >> 3;
    {
        float acc[7];
        #pragma unroll
        for (int r = 0; r < 7; ++r) acc[r] = 0.f;
        for (int sc = 0; sc < 13; ++sc) {
            float4 hv0 = *(const float4*)&s_hWd[cc * BPAD + sc * 8];
            float4 hv1 = *(const float4*)&s_hWd[cc * BPAD + sc * 8 + 4];
            #pragma unroll
            for (int r = 0; r < 7; ++r) {
                int d = dg + 16 * r;
                half8 m = *(const half8*)&M[d * BPAD + sc * 8];
                acc[r] += (float)m[0]*hv0.x + (float)m[1]*hv0.y + (float)m[2]*hv0.z + (float)m[3]*hv0.w
                        + (float)m[4]*hv1.x + (float)m[5]*hv1.y + (float)m[6]*hv1.z + (float)m[7]*hv1.w;
            }
        }
        float bc = gcn_b[c0 + cc];
        #pragma unroll
        for (int r = 0; r < 7; ++r) {
            int d = dg + 16 * r;
            if (d < BINSZ) {
                float g = s_dis[d] * (acc[r] + s_hWd[cc * BPAD + d]) + bc;
                s_gcn[cc * BPAD + d] = g;
                gcn_n[s_nodes[d] * 32 + c0 + cc] = g;
            }
        }
    }
    __syncthreads();
    {
        float acc[7];
        #pragma unroll
        for (int r = 0; r < 7; ++r) acc[r] = 0.f;
        for (int sc = 0; sc < 13; ++sc) {
            float4 hv0 = *(const float4*)&s_gcn[cc * BPAD + sc * 8];
            float4 hv1 = *(const float4*)&s_gcn[cc * BPAD + sc * 8 + 4];
            #pragma unroll
            for (int r = 0; r < 7; ++r) {
                int d = dg + 16 * r;
                half8 m = *(const half8*)&M[d * BPAD + sc * 8];
                acc[r] += (float)m[0]*hv0.x + (float)m[1]*hv0.y + (float)m[2]*hv0.z + (float)m[3]*hv0.w
                        + (float)m[4]*hv1.x + (float)m[5]*hv1.y + (float)m[6]*hv1.z + (float)m[7]*hv1.w;
            }
        }
        #pragma unroll
        for (int r = 0; r < 7; ++r) {
            int d = dg + 16 * r;
            if (d < BINSZ) agg_n[s_nodes[d] * 32 + c0 + cc] = acc[r];
        }
    }
}

// =================== fused combine + nn2 + nn3 (LDS-staged weights) =================
__global__ __launch_bounds__(128) void nn23_kernel(
    const float* __restrict__ gcn_n, const float* __restrict__ agg_n,
    const float* __restrict__ Wrel, const float* __restrict__ brel,
    const float* __restrict__ Wroot,
    const float* __restrict__ A1, const float* __restrict__ ab1,
    const float* __restrict__ A2, const float* __restrict__ ab2,
    const float* __restrict__ A3, const float* __restrict__ ab3,
    const float* __restrict__ B1, const float* __restrict__ bb1,
    const float* __restrict__ B2, const float* __restrict__ bb2,
    const float* __restrict__ B3, const float* __restrict__ bb3,
    float* __restrict__ out_ids, float* __restrict__ out_p4) {
    __shared__ float sW[8000];          // 32 KB weight stage
    __shared__ float s_ag[32 * MN];     // transposed [k][n]
    __shared__ float s_gc[32 * MN];
    __shared__ float sIN[38 * MN];      // [k][n]; rows 32..37 = ids
    __shared__ float sA[125 * MN];
    __shared__ float sB[125 * MN];
    int tid = threadIdx.x;
    int n0 = blockIdx.x * MN;
    float acc[MN];

    // stage agg/gcn transposed + Wrel/Wroot
    for (int t = tid; t < MN * 32; t += 128) {
        int n = t >> 5, k = t & 31;
        s_ag[k * MN + n] = agg_n[(n0 + n) * 32 + k];
        s_gc[k * MN + n] = gcn_n[(n0 + n) * 32 + k];
    }
    for (int t = tid; t < 256; t += 128) {
        ((float4*)sW)[t] = ((const float4*)Wrel)[t];
        ((float4*)(sW + 1024))[t] = ((const float4*)Wroot)[t];
    }
    __syncthreads();
    // combine: sIN[j][n] = leaky(agg@Wrel + brel + gcn@Wroot)
    for (int o = tid; o < 256; o += 128) {
        int j = o >> 3, n = o & 7;
        float a = brel[j];
        #pragma unroll 8
        for (int k = 0; k < 32; ++k)
            a += s_ag[k * MN + n] * sW[k * 32 + j] + s_gc[k * MN + n] * sW[1024 + k * 32 + j];
        sIN[j * MN + n] = lrelu(a);
    }
    __syncthreads();
    // nn2 L1: 32 -> 125  (stage A1: 4000 floats)
    for (int t = tid; t < 1000; t += 128) ((float4*)sW)[t] = ((const float4*)A1)[t];
    __syncthreads();
    if (tid < 125) {
        int j = tid;
        #pragma unroll
        for (int n = 0; n < MN; ++n) acc[n] = ab1[j];
        #pragma unroll 4
        for (int k = 0; k < 32; ++k) {
            float w = sW[k * 125 + j];
            const float4* hp = (const float4*)&sIN[k * MN];
            float4 h0 = hp[0], h1 = hp[1];
            acc[0]+=h0.x*w; acc[1]+=h0.y*w; acc[2]+=h0.z*w; acc[3]+=h0.w*w;
            acc[4]+=h1.x*w; acc[5]+=h1.y*w; acc[6]+=h1.z*w; acc[7]+=h1.w*w;
        }
        #pragma unroll
        for (int n = 0; n < MN; ++n) sA[tid * MN + n] = lrelu(acc[n]);
    }
    __syncthreads();
    // nn2 L2: 125 -> 125 (A2 staged in 64 + 61 row chunks)
    for (int t = tid; t < 2000; t += 128) ((float4*)sW)[t] = ((const float4*)A2)[t];
    __syncthreads();
    if (tid < 125) {
        int j = tid;
        #pragma unroll
        for (int n = 0; n < MN; ++n) acc[n] = ab2[j];
        #pragma unroll 4
        for (int k = 0; k < 64; ++k) {
            float w = sW[k * 125 + j];
            const float4* hp = (const float4*)&sA[k * MN];
            float4 h0 = hp[0], h1 = hp[1];
            acc[0]+=h0.x*w; acc[1]+=h0.y*w; acc[2]+=h0.z*w; acc[3]+=h0.w*w;
            acc[4]+=h1.x*w; acc[5]+=h1.y*w; acc[6]+=h1.z*w; acc[7]+=h1.w*w;
        }
    }
    __syncthreads();
    for (int t = tid; t < 1906; t += 128) ((float4*)sW)[t] = ((const float4*)(A2 + 8000))[t];
    if (tid == 0) sW[7624] = A2[8000 + 7624];
    __syncthreads();
    if (tid < 125) {
        int j = tid;
        #pragma unroll 4
        for (int k = 0; k < 61; ++k) {
            float w = sW[k * 125 + j];
            const float4* hp = (const float4*)&sA[(64 + k) * MN];
            float4 h0 = hp[0], h1 = hp[1];
            acc[0]+=h0.x*w; acc[1]+=h0.y*w; acc[2]+=h0.z*w; acc[3]+=h0.w*w;
            acc[4]+=h1.x*w; acc[5]+=h1.y*w; acc[6]+=h1.z*w; acc[7]+=h1.w*w;
        }
        #pragma unroll
        for (int n = 0; n < MN; ++n) sB[tid * MN + n] = lrelu(acc[n]);
    }
    __syncthreads();
    // stage A3 (750 @ sW[0..750)) and B1 (4750 @ sW[752..5502))
    for (int t = tid; t < 187; t += 128) ((float4*)sW)[t] = ((const float4*)A3)[t];
    if (tid < 2) sW[748 + tid] = A3[748 + tid];
    for (int t = tid; t < 1187; t += 128) ((float4*)(sW + 752))[t] = ((const float4*)B1)[t];
    if (tid < 2) sW[752 + 4748 + tid] = B1[4748 + tid];
    __syncthreads();
    // nn2 L3: 125 -> 6 (k-split), partials -> sA rows 0..11
    {
        int half = (tid >= 64), j = half ? tid - 64 : tid;
        if (j < 6) {
            int k0 = half ? 63 : 0, k1 = half ? 125 : 63;
            float ps[MN];
            #pragma unroll
            for (int n = 0; n < MN; ++n) ps[n] = 0.f;
            for (int k = k0; k < k1; ++k) {
                float w = sW[k * 6 + j];
                const float4* hp = (const float4*)&sB[k * MN];
                float4 h0 = hp[0], h1 = hp[1];
                ps[0]+=h0.x*w; ps[1]+=h0.y*w; ps[2]+=h0.z*w; ps[3]+=h0.w*w;
                ps[4]+=h1.x*w; ps[5]+=h1.y*w; ps[6]+=h1.z*w; ps[7]+=h1.w*w;
            }
            #pragma unroll
            for (int n = 0; n < MN; ++n) sA[(half * 6 + j) * MN + n] = ps[n];
        }
    }
    __syncthreads();
    if (tid < 6) {
        int j = tid;
        float bj = ab3[j];
        #pragma unroll
        for (int n = 0; n < MN; ++n) {
            float v = sA[j * MN + n] + sA[(6 + j) * MN + n] + bj;
            out_ids[(n0 + n) * 6 + j] = v;
            sIN[(32 + j) * MN + n] = v;
        }
    }
    __syncthreads();
    // nn3 L1: 38 -> 125 (B1 at sW+752) -> sA
    if (tid < 125) {
        int j = tid;
        #pragma unroll
        for (int n = 0; n < MN; ++n) acc[n] = bb1[j];
        #pragma unroll 2
        for (int k = 0; k < 38; ++k) {
            float w = sW[752 + k * 125 + j];
            const float4* hp = (const float4*)&sIN[k * MN];
            float4 h0 = hp[0], h1 = hp[1];
            acc[0]+=h0.x*w; acc[1]+=h0.y*w; acc[2]+=h0.z*w; acc[3]+=h0.w*w;
            acc[4]+=h1.x*w; acc[5]+=h1.y*w; acc[6]+=h1.z*w; acc[7]+=h1.w*w;
        }
        #pragma unroll
        for (int n = 0; n < MN; ++n) sA[tid * MN + n] = lrelu(acc[n]);
    }
    __syncthreads();
    // nn3 L2: 125 -> 125 (B2 chunks) -> sB
    for (int t = tid; t < 2000; t += 128) ((float4*)sW)[t] = ((const float4*)B2)[t];
    __syncthreads();
    if (tid < 125) {
        int j = tid;
        #pragma unroll
        for (int n = 0; n < MN; ++n) acc[n] = bb2[j];
        #pragma unroll 4
        for (int k = 0; k < 64; ++k) {
            float w = sW[k * 125 + j];
            const float4* hp = (const float4*)&sA[k * MN];
            float4 h0 = hp[0], h1 = hp[1];
            acc[0]+=h0.x*w; acc[1]+=h0.y*w; acc[2]+=h0.z*w; acc[3]+=h0.w*w;
            acc[4]+=h1.x*w; acc[5]+=h1.y*w; acc[6]+=h1.z*w; acc[7]+=h1.w*w;
        }
    }
    __syncthreads();
    for (int t = tid; t < 1906; t += 128) ((float4*)sW)[t] = ((const float4*)(B2 + 8000))[t];
    if (tid == 0) sW[7624] = B2[8000 + 7624];
    __syncthreads();
    if (tid < 125) {
        int j = tid;
        #pragma unroll 4
        for (int k = 0; k < 61; ++k) {
            float w = sW[k * 125 + j];
            const float4* hp = (const float4*)&sA[(64 + k) * MN];
            float4 h0 = hp[0], h1 = hp[1];
            acc[0]+=h0.x*w; acc[1]+=h0.y*w; acc[2]+=h0.z*w; acc[3]+=h0.w*w;
            acc[4]+=h1.x*w; acc[5]+=h1.y*w; acc[6]+=h1.z*w; acc[7]+=h1.w*w;
        }
        #pragma unroll
        for (int n = 0; n < MN; ++n) sB[tid * MN + n] = lrelu(acc[n]);
    }
    __syncthreads();
    // nn3 L3: 125 -> 6 (B3), k-split, partials -> sIN rows 0..11
    for (int t = tid; t < 187; t += 128) ((float4*)sW)[t] = ((const float4*)B3)[t];
    if (tid < 2) sW[748 + tid] = B3[748 + tid];
    __syncthreads();
    {
        int half = (tid >= 64), j = half ? tid - 64 : tid;
        if (j < 6) {
            int k0 = half ? 63 : 0, k1 = half ? 125 : 63;
            float ps[MN];
            #pragma unroll
            for (int n = 0; n < MN; ++n) ps[n] = 0.f;
            for (int k = k0; k < k1; ++k) {
                float w = sW[k * 6 + j];
                const float4* hp = (const float4*)&sB[k * MN];
                float4 h0 = hp[0], h1 = hp[1];
                ps[0]+=h0.x*w; ps[1]+=h0.y*w; ps[2]+=h0.z*w; ps[3]+=h0.w*w;
                ps[4]+=h1.x*w; ps[5]+=h1.y*w; ps[6]+=h1.z*w; ps[7]+=h1.w*w;
            }
            #pragma unroll
            for (int n = 0; n < MN; ++n) sIN[(half * 6 + j) * MN + n] = ps[n];
        }
    }
    __syncthreads();
    if (tid < 6) {
        int j = tid;
        float bj = bb3[j];
        #pragma unroll
        for (int n = 0; n < MN; ++n)
            out_p4[(n0 + n) * 6 + j] = sIN[j * MN + n] + sIN[(6 + j) * MN + n] + bj;
    }
}

static inline int cdiv(int a, int b) { return (a + b - 1) / b; }

extern "C" void kernel_launch(void* const* d_in, const int* in_sizes, int n_in,
                              void* d_out, int out_size, void* d_ws, size_t ws_size,
                              hipStream_t stream) {
    const float* x        = (const float*)d_in[0];
    const float* ygen_id  = (const float*)d_in[1];
    const float* ygen     = (const float*)d_in[2];
    const float* codebook = (const float*)d_in[3];
    const float* nn1_W1 = (const float*)d_in[4];  const float* nn1_b1 = (const float*)d_in[5];
    const float* nn1_W2 = (const float*)d_in[6];  const float* nn1_b2 = (const float*)d_in[7];
    const float* nn1_W3 = (const float*)d_in[8];  const float* nn1_b3 = (const float*)d_in[9];
    const float* gcn_W  = (const float*)d_in[10]; const float* gcn_b  = (const float*)d_in[11];
    const float* gc_Wrel = (const float*)d_in[12]; const float* gc_brel = (const float*)d_in[13];
    const float* gc_Wroot = (const float*)d_in[14];
    const float* nn2_W1 = (const float*)d_in[15]; const float* nn2_b1 = (const float*)d_in[16];
    const float* nn2_W2 = (const float*)d_in[17]; const float* nn2_b2 = (const float*)d_in[18];
    const float* nn2_W3 = (const float*)d_in[19]; const float* nn2_b3 = (const float*)d_in[20];
    const float* nn3_W1 = (const float*)d_in[21]; const float* nn3_b1 = (const float*)d_in[22];
    const float* nn3_W2 = (const float*)d_in[23]; const float* nn3_b2 = (const float*)d_in[24];
    const float* nn3_W3 = (const float*)d_in[25]; const float* nn3_b3 = (const float*)d_in[26];

    float* out = (float*)d_out;
    float* ws  = (float*)d_ws;

    float* h      = ws + 0;         // 60000
    float* gcn_n  = ws + 60000;     // 160000
    float* agg_n  = ws + 220000;    // 160000
    float* dis_g  = ws + 380000;    // 5000
    _Float16* Mg  = (_Float16*)(ws + 385000);   // 520000 halves
    int* bin_idx  = (int*)(ws + 645000);        // 5000
    int* order    = (int*)(ws + 650000);        // 5000

    nn1_kernel<<<NN / MN, 128, 0, stream>>>(
        x, nn1_W1, nn1_b1, nn1_W2, nn1_b2, nn1_W3, nn1_b3, codebook,
        h, bin_idx);

    scatter_kernel<<<NBINS, 64, 0, stream>>>(
        bin_idx, order, (const float4*)ygen_id, (const float4*)ygen, (float4*)out);

    build_kernel<<<NBINS, 256, 0, stream>>>(h, order, Mg, dis_g);

    conv_kernel<<<NBINS * 4, 128, 0, stream>>>(
        Mg, dis_g, h, order, gcn_W, gcn_b, gcn_n, agg_n);

    nn23_kernel<<<NN / MN, 128, 0, stream>>>(
        gcn_n, agg_n, gc_Wrel, gc_brel, gc_Wroot,
        nn2_W1, nn2_b1, nn2_W2, nn2_b2, nn2_W3, nn2_b3,
        nn3_W1, nn3_b1, nn3_W2, nn3_b2, nn3_W3, nn3_b3,
        out, out + 30000);
}

// Round 8
// 215.558 us; speedup vs baseline: 4.0066x; 1.1655x over previous
//
#include <hip/hip_runtime.h>
#include <math.h>

#define NN 5000
#define NBINS 50
#define BINSZ 100
#define KNN 16
#define BPAD 104          // padded M row length (halves); 208 B stride, 16B aligned
#define MROWS 112         // padded row count in conv kernel
#define NB 20             // nodes per block in MLP kernels (5 groups x 4)

typedef _Float16 half8 __attribute__((ext_vector_type(8)));

__device__ __forceinline__ float lrelu(float x){ return x >= 0.f ? x : 0.01f*x; }

// =================== fused MLP1 + LSH bin: 250 blocks x 640 thr, 20 nodes/block =====
// Weights staged in LDS; 125x125 layer uses register-prefetch double-buffered chunks.
__global__ __launch_bounds__(640) void nn1_kernel(
    const float* __restrict__ x,
    const float* __restrict__ W1, const float* __restrict__ b1,
    const float* __restrict__ W2, const float* __restrict__ b2,
    const float* __restrict__ W3, const float* __restrict__ b3,
    const float* __restrict__ cb,
    float* __restrict__ h_out, int* __restrict__ bin_idx) {
    __shared__ float sW[8000];        // 2 x 4000 (32x125) chunk buffers
    __shared__ float bufX[12 * NB];
    __shared__ float bufA[125 * NB];
    __shared__ float bufB[125 * NB];
    __shared__ float sCB[300];
    int tid = threadIdx.x;
    int n0 = blockIdx.x * NB;         // 250 * 20 = 5000
    int g = tid >> 7, j = tid & 127;  // 5 groups x 128 (125 active)
    float acc[4];
    float4 r0, r1; float rt = 0.f;

    // ---- stage x (transposed [k][n]), codebook, W1 ----
    if (tid < 60) {
        float4 v = ((const float4*)(x + n0 * 12))[tid];
        int e = tid * 4;
        bufX[(e % 12) * NB + (e / 12)] = v.x;
        bufX[((e + 1) % 12) * NB + ((e + 1) / 12)] = v.y;
        bufX[((e + 2) % 12) * NB + ((e + 2) / 12)] = v.z;
        bufX[((e + 3) % 12) * NB + ((e + 3) / 12)] = v.w;
    }
    if (tid < 300) { int k = tid / 25, c = tid - k * 25; sCB[tid] = cb[k * 100 + c]; }
    if (tid < 375) ((float4*)sW)[tid] = ((const float4*)W1)[tid];   // 1500 floats
    __syncthreads();

    // ---- L1: 12 -> 125, leaky -> bufA[k][20] ----
    if (j < 125) {
        float bj = b1[j];
        acc[0] = bj; acc[1] = bj; acc[2] = bj; acc[3] = bj;
        #pragma unroll
        for (int k = 0; k < 12; ++k) {
            float w = sW[k * 125 + j];
            float4 a = *(const float4*)&bufX[k * NB + g * 4];
            acc[0] += a.x * w; acc[1] += a.y * w; acc[2] += a.z * w; acc[3] += a.w * w;
        }
        #pragma unroll
        for (int n = 0; n < 4; ++n) bufA[j * NB + g * 4 + n] = lrelu(acc[n]);
    }
    // prefetch W2 chunk0 (1000 float4: [tid] + [tid+640] halves)
    r0 = (tid < 1000) ? ((const float4*)W2)[tid] : make_float4(0.f,0.f,0.f,0.f);
    r1 = (tid < 360)  ? ((const float4*)W2)[tid + 640] : make_float4(0.f,0.f,0.f,0.f);
    __syncthreads();
    if (tid < 1000) ((float4*)sW)[tid] = r0;
    if (tid < 360)  ((float4*)sW)[tid + 640] = r1;
    __syncthreads();

    // ---- L2: 125 -> 125, chunked (32/32/32/29 rows), reg-prefetch dbuf ----
    if (j < 125) { float bj = b2[j]; acc[0] = bj; acc[1] = bj; acc[2] = bj; acc[3] = bj; }
    for (int c = 0; c < 4; ++c) {
        if (c < 3) {
            int base = (c + 1) * 1000, nf4 = (c + 1 < 3) ? 1000 : 906;
            r0 = (tid < nf4) ? ((const float4*)W2)[base + tid] : make_float4(0.f,0.f,0.f,0.f);
            r1 = (tid + 640 < nf4) ? ((const float4*)W2)[base + tid + 640] : make_float4(0.f,0.f,0.f,0.f);
            if (c + 1 == 3 && tid == 0) rt = W2[15624];
        }
        int nk = (c < 3) ? 32 : 29;
        const float* wbuf = sW + (c & 1) * 4000;
        if (j < 125) {
            const float* arow = &bufA[(c * 32) * NB + g * 4];
            for (int k = 0; k < nk; ++k) {
                float w = wbuf[k * 125 + j];
                float4 a = *(const float4*)&arow[k * NB];
                acc[0] += a.x * w; acc[1] += a.y * w; acc[2] += a.z * w; acc[3] += a.w * w;
            }
        }
        if (c < 3) {
            float* dst = sW + ((c + 1) & 1) * 4000;
            int nf4 = (c + 1 < 3) ? 1000 : 906;
            if (tid < nf4) ((float4*)dst)[tid] = r0;
            if (tid + 640 < nf4) ((float4*)dst)[tid + 640] = r1;
            if (c + 1 == 3 && tid == 0) dst[3624] = rt;
            __syncthreads();
        }
    }
    if (j < 125) {
        #pragma unroll
        for (int n = 0; n < 4; ++n) bufB[j * NB + g * 4 + n] = lrelu(acc[n]);
    }
    // stage W3 (375 float4 -> buf0; chunk3 compute used buf1, disjoint)
    __syncthreads();
    if (tid < 375) ((float4*)sW)[tid] = ((const float4*)W3)[tid];
    __syncthreads();

    // ---- L3: 125 -> 12, 4-way k-split (32/32/32/29) ----
    if (j < 48) {
        int jj = j % 12, s = j / 12;
        int k0 = s * 32, nk = (s < 3) ? 32 : 29;
        float ps[4] = {0.f, 0.f, 0.f, 0.f};
        for (int k = 0; k < nk; ++k) {
            float w = sW[(k0 + k) * 12 + jj];
            float4 a = *(const float4*)&bufB[(k0 + k) * NB + g * 4];
            ps[0] += a.x * w; ps[1] += a.y * w; ps[2] += a.z * w; ps[3] += a.w * w;
        }
        #pragma unroll
        for (int n = 0; n < 4; ++n) bufA[(s * 12 + jj) * NB + g * 4 + n] = ps[n];
    }
    __syncthreads();
    if (tid < 240) {
        int jj = tid / 20, n = tid % 20;
        float v = bufA[jj * NB + n] + bufA[(12 + jj) * NB + n]
                + bufA[(24 + jj) * NB + n] + bufA[(36 + jj) * NB + n] + b3[jj];
        h_out[(n0 + n) * 12 + jj] = v;
        bufB[jj * NB + n] = v;
    }
    __syncthreads();

    // ---- LSH bin (argmax over [mul,-mul], first max wins) ----
    if (tid < NB) {
        int n = tid;
        float hv[12];
        #pragma unroll
        for (int k = 0; k < 12; ++k) hv[k] = bufB[k * NB + n];
        float best = -INFINITY; int bi = 0;
        for (int c = 0; c < 25; ++c) {
            float m = 0.f;
            #pragma unroll
            for (int k = 0; k < 12; ++k) m += hv[k] * sCB[k * 25 + c];
            if (m > best) { best = m; bi = c; }
        }
        for (int c = 0; c < 25; ++c) {
            float m = 0.f;
            #pragma unroll
            for (int k = 0; k < 12; ++k) m += hv[k] * sCB[k * 25 + c];
            if (-m > best) { best = -m; bi = c + 25; }
        }
        bin_idx[n0 + n] = bi;
    }
}

// =================== stable argsort-by-bin (LDS-staged) + ygen passthrough ==========
__global__ __launch_bounds__(64) void scatter_kernel(
    const int* __restrict__ bin_idx, int* __restrict__ order,
    const float4* __restrict__ ygen_id4, const float4* __restrict__ ygen4,
    float4* __restrict__ out4) {
    __shared__ int sBI[NN];
    int b = blockIdx.x, lane = threadIdx.x;
    for (int t = lane; t < NN / 4; t += 64) ((int4*)sBI)[t] = ((const int4*)bin_idx)[t];
    for (int t = lane; t < 300; t += 64) {
        int g = b * 300 + t;
        out4[15000 + g] = (g < 7500) ? ygen_id4[g] : ygen4[g - 7500];
    }
    __syncthreads();
    unsigned long long below = (lane == 0) ? 0ULL : ((~0ULL) >> (64 - lane));
    int cnt_lt = 0;
    for (int base = 0; base < NN; base += 64) {
        int i = base + lane;
        int bi = (i < NN) ? sBI[i] : 999;
        cnt_lt += __popcll(__ballot(bi < b));
    }
    int offs = cnt_lt;
    for (int base = 0; base < NN; base += 64) {
        int i = base + lane;
        int bi = (i < NN) ? sBI[i] : 999;
        unsigned long long m = __ballot(bi == b);
        if (bi == b) order[offs + __popcll(m & below)] = i;
        offs += __popcll(m);
    }
}

// =================== K1: build dense fp16 edge matrix M + dis (50 blocks) ===========
__global__ __launch_bounds__(256) void build_kernel(
    const float* __restrict__ h, const int* __restrict__ order,
    _Float16* __restrict__ Mg, float* __restrict__ dis_g) {
    __shared__ _Float16 M[BINSZ * BPAD];
    __shared__ float s_h[BINSZ * 12];
    __shared__ int   s_nodes[BINSZ];
    __shared__ float s_tv[200 * KNN];
    __shared__ int   s_tix[200 * KNN];
    int p = blockIdx.x, tid = threadIdx.x;

    if (tid < BINSZ) s_nodes[tid] = order[p * BINSZ + tid];
    for (int t = tid; t < BINSZ * BPAD / 2; t += 256) ((int*)M)[t] = 0;
    __syncthreads();
    for (int t = tid; t < BINSZ * 12; t += 256) {
        int i = t / 12, k = t - i * 12;
        s_h[t] = h[s_nodes[i] * 12 + k];
    }
    __syncthreads();

    if (tid < 200) {
        int row = tid >> 1, half = tid & 1;
        const float4* xp = (const float4*)&s_h[row * 12];
        float4 x0 = xp[0], x1 = xp[1], x2 = xp[2];
        float tv[KNN]; int ti[KNN];
        #pragma unroll
        for (int k = 0; k < KNN; ++k) { tv[k] = -1e30f; ti[k] = 0; }
        int j0 = half * 50;
        for (int jj = 0; jj < 50; ++jj) {
            int j = j0 + jj;
            const float4* ap = (const float4*)&s_h[j * 12];
            float4 a0 = ap[0], a1 = ap[1], a2 = ap[2];
            float d = x0.x*a0.x + x0.y*a0.y + x0.z*a0.z + x0.w*a0.w
                    + x1.x*a1.x + x1.y*a1.y + x1.z*a1.z + x1.w*a1.w
                    + x2.x*a2.x + x2.y*a2.y + x2.z*a2.z + x2.w*a2.w;
            float v = 1.f / (1.f + expf(-d));
            if (v > tv[KNN - 1]) {
                int vi = j;
                #pragma unroll
                for (int k = 0; k < KNN; ++k) {
                    bool gt = v > tv[k];
                    float nv = gt ? v : tv[k];  int ni = gt ? vi : ti[k];
                    float ov = gt ? tv[k] : v;  int oi = gt ? ti[k] : vi;
                    tv[k] = nv; ti[k] = ni; v = ov; vi = oi;
                }
            }
        }
        #pragma unroll
        for (int k = 0; k < KNN; ++k) {
            s_tv[tid * KNN + k] = tv[k];
            s_tix[tid * KNN + k] = ti[k];
        }
    }
    __syncthreads();

    if (tid < BINSZ) {
        int base = tid * 32;
        int ia = 0, ib = 0;
        #pragma unroll
        for (int k = 0; k < KNN; ++k) {
            float av = s_tv[base + ia], bv = s_tv[base + 16 + ib];
            bool tA = av >= bv;
            float v = tA ? av : bv;
            int ix = tA ? s_tix[base + ia] : s_tix[base + 16 + ib];
            ia += tA; ib += !tA;
            M[ix * BPAD + tid] = (_Float16)v;
        }
    }
    __syncthreads();

    for (int t = tid; t < BINSZ * BPAD / 8; t += 256)
        ((uint4*)(Mg + (size_t)p * BINSZ * BPAD))[t] = ((const uint4*)M)[t];
    if (tid < BINSZ) {
        float dsum = 1.0f;
        #pragma unroll 13
        for (int sc = 0; sc < 13; ++sc) {
            half8 m = *(const half8*)&M[tid * BPAD + sc * 8];
            dsum += (float)m[0] + (float)m[1] + (float)m[2] + (float)m[3]
                  + (float)m[4] + (float)m[5] + (float)m[6] + (float)m[7];
        }
        dis_g[p * BINSZ + tid] = 1.0f / sqrtf(dsum);
    }
}

// =================== K2: channel-sliced convs (200 blocks) ==========================
__global__ __launch_bounds__(128) void conv_kernel(
    const _Float16* __restrict__ Mg, const float* __restrict__ dis_g,
    const float* __restrict__ h, const int* __restrict__ order,
    const float* __restrict__ gcn_W, const float* __restrict__ gcn_b,
    float* __restrict__ gcn_n, float* __restrict__ agg_n) {
    __shared__ _Float16 M[MROWS * BPAD];
    __shared__ float s_h[BINSZ * 12];
    __shared__ int   s_nodes[BINSZ];
    __shared__ float s_dis[BINSZ];
    __shared__ float s_w[12 * 8];
    __shared__ float s_hWd[8 * BPAD];
    __shared__ float s_gcn[8 * BPAD];
    int bid = blockIdx.x, tid = threadIdx.x;
    int p = bid >> 2, cg = bid & 3, c0 = cg * 8;

    if (tid < BINSZ) {
        s_nodes[tid] = order[p * BINSZ + tid];
        s_dis[tid]   = dis_g[p * BINSZ + tid];
    }
    for (int t = tid; t < 96; t += 128)
        s_w[t] = gcn_W[(t >> 3) * 32 + c0 + (t & 7)];
    for (int t = tid; t < BINSZ * BPAD / 8; t += 128)
        ((uint4*)M)[t] = ((const uint4*)(Mg + (size_t)p * BINSZ * BPAD))[t];
    for (int t = tid; t < (MROWS - BINSZ) * BPAD / 2; t += 128)
        ((int*)(M + BINSZ * BPAD))[t] = 0;
    if (tid < 32) {
        s_hWd[(tid >> 2) * BPAD + 100 + (tid & 3)] = 0.f;
        s_gcn[(tid >> 2) * BPAD + 100 + (tid & 3)] = 0.f;
    }
    __syncthreads();
    for (int t = tid; t < BINSZ * 12; t += 128) {
        int i = t / 12, k = t - i * 12;
        s_h[t] = h[s_nodes[i] * 12 + k];
    }
    __syncthreads();

    for (int o = tid; o < BINSZ * 8; o += 128) {
        int s = o >> 3, cc = o & 7;
        float a = 0.f;
        #pragma unroll
        for (int k = 0; k < 12; ++k) a += lrelu(s_h[s * 12 + k]) * s_w[k * 8 + cc];
        s_hWd[cc * BPAD + s] = s_dis[s] * a;
    }
    __syncthreads();

    int cc = tid & 7, dg = tid >> 3;
    {
        float acc[7];
        #pragma unroll
        for (int r = 0; r < 7; ++r) acc[r] = 0.f;
        for (int sc = 0; sc < 13; ++sc) {
            float4 hv0 = *(const float4*)&s_hWd[cc * BPAD + sc * 8];
            float4 hv1 = *(const float4*)&s_hWd[cc * BPAD + sc * 8 + 4];
            #pragma unroll
            for (int r = 0; r < 7; ++r) {
                int d = dg + 16 * r;
                half8 m = *(const half8*)&M[d * BPAD + sc * 8];
                acc[r] += (float)m[0]*hv0.x + (float)m[1]*hv0.y + (float)m[2]*hv0.z + (float)m[3]*hv0.w
                        + (float)m[4]*hv1.x + (float)m[5]*hv1.y + (float)m[6]*hv1.z + (float)m[7]*hv1.w;
            }
        }
        float bc = gcn_b[c0 + cc];
        #pragma unroll
        for (int r = 0; r < 7; ++r) {
            int d = dg + 16 * r;
            if (d < BINSZ) {
                float gq = s_dis[d] * (acc[r] + s_hWd[cc * BPAD + d]) + bc;
                s_gcn[cc * BPAD + d] = gq;
                gcn_n[s_nodes[d] * 32 + c0 + cc] = gq;
            }
        }
    }
    __syncthreads();
    {
        float acc[7];
        #pragma unroll
        for (int r = 0; r < 7; ++r) acc[r] = 0.f;
        for (int sc = 0; sc < 13; ++sc) {
            float4 hv0 = *(const float4*)&s_gcn[cc * BPAD + sc * 8];
            float4 hv1 = *(const float4*)&s_gcn[cc * BPAD + sc * 8 + 4];
            #pragma unroll
            for (int r = 0; r < 7; ++r) {
                int d = dg + 16 * r;
                half8 m = *(const half8*)&M[d * BPAD + sc * 8];
                acc[r] += (float)m[0]*hv0.x + (float)m[1]*hv0.y + (float)m[2]*hv0.z + (float)m[3]*hv0.w
                        + (float)m[4]*hv1.x + (float)m[5]*hv1.y + (float)m[6]*hv1.z + (float)m[7]*hv1.w;
            }
        }
        #pragma unroll
        for (int r = 0; r < 7; ++r) {
            int d = dg + 16 * r;
            if (d < BINSZ) agg_n[s_nodes[d] * 32 + c0 + cc] = acc[r];
        }
    }
}

// =================== fused combine + nn2 + nn3: 250 blocks x 640 thr ================
__global__ __launch_bounds__(640) void nn23_kernel(
    const float* __restrict__ gcn_n, const float* __restrict__ agg_n,
    const float* __restrict__ Wrel, const float* __restrict__ brel,
    const float* __restrict__ Wroot,
    const float* __restrict__ A1, const float* __restrict__ ab1,
    const float* __restrict__ A2, const float* __restrict__ ab2,
    const float* __restrict__ A3, const float* __restrict__ ab3,
    const float* __restrict__ B1, const float* __restrict__ bb1,
    const float* __restrict__ B2, const float* __restrict__ bb2,
    const float* __restrict__ B3, const float* __restrict__ bb3,
    float* __restrict__ out_ids, float* __restrict__ out_p4) {
    __shared__ float sW[8000];          // 2 x 4000 chunk buffers / small-weight arena
    __shared__ float sAG[32 * NB];      // [k][n]
    __shared__ float sGC[32 * NB];
    __shared__ float bufC[38 * NB];     // combine out rows 0..31, ids rows 32..37
    __shared__ float bufA[125 * NB];
    __shared__ float bufB[125 * NB];
    int tid = threadIdx.x;
    int n0 = blockIdx.x * NB;
    int g = tid >> 7, j = tid & 127;
    float acc[4];
    float4 r0, r1; float rt = 0.f;

    // ---- stage agg/gcn transposed + Wrel/Wroot ----
    if (tid < 160) {
        float4 va = ((const float4*)(agg_n + n0 * 32))[tid];
        float4 vg = ((const float4*)(gcn_n + n0 * 32))[tid];
        int e = tid * 4, n = e / 32, k = e % 32;
        sAG[k * NB + n] = va.x; sAG[(k+1) * NB + n] = va.y;
        sAG[(k+2) * NB + n] = va.z; sAG[(k+3) * NB + n] = va.w;
        sGC[k * NB + n] = vg.x; sGC[(k+1) * NB + n] = vg.y;
        sGC[(k+2) * NB + n] = vg.z; sGC[(k+3) * NB + n] = vg.w;
    }
    if (tid < 256) ((float4*)sW)[tid] = ((const float4*)Wrel)[tid];
    else if (tid < 512) ((float4*)(sW + 1024))[tid - 256] = ((const float4*)Wroot)[tid - 256];
    __syncthreads();

    // ---- combine: bufC[jc][n] = leaky(agg@Wrel + brel + gcn@Wroot), 32x20=640 thr ---
    {
        int jc = tid / 20, n = tid % 20;
        float a = brel[jc];
        #pragma unroll 8
        for (int k = 0; k < 32; ++k)
            a += sAG[k * NB + n] * sW[k * 32 + jc] + sGC[k * NB + n] * sW[1024 + k * 32 + jc];
        bufC[jc * NB + n] = lrelu(a);
    }
    __syncthreads();
    // stage A1 (1000 float4) — grid-stride: 640 threads must cover all 1000!
    for (int t = tid; t < 1000; t += 640) ((float4*)sW)[t] = ((const float4*)A1)[t];
    __syncthreads();

    // ---- nn2 L1: 32 -> 125 ----
    if (j < 125) {
        float bj = ab1[j];
        acc[0] = bj; acc[1] = bj; acc[2] = bj; acc[3] = bj;
        #pragma unroll 8
        for (int k = 0; k < 32; ++k) {
            float w = sW[k * 125 + j];
            float4 a = *(const float4*)&bufC[k * NB + g * 4];
            acc[0] += a.x * w; acc[1] += a.y * w; acc[2] += a.z * w; acc[3] += a.w * w;
        }
        #pragma unroll
        for (int n = 0; n < 4; ++n) bufA[j * NB + g * 4 + n] = lrelu(acc[n]);
    }
    // prefetch A2 chunk0
    r0 = (tid < 1000) ? ((const float4*)A2)[tid] : make_float4(0.f,0.f,0.f,0.f);
    r1 = (tid < 360)  ? ((const float4*)A2)[tid + 640] : make_float4(0.f,0.f,0.f,0.f);
    __syncthreads();
    if (tid < 1000) ((float4*)sW)[tid] = r0;
    if (tid < 360)  ((float4*)sW)[tid + 640] = r1;
    __syncthreads();

    // ---- nn2 L2: 125 -> 125, chunked dbuf ----
    if (j < 125) { float bj = ab2[j]; acc[0] = bj; acc[1] = bj; acc[2] = bj; acc[3] = bj; }
    for (int c = 0; c < 4; ++c) {
        if (c < 3) {
            int base = (c + 1) * 1000, nf4 = (c + 1 < 3) ? 1000 : 906;
            r0 = (tid < nf4) ? ((const float4*)A2)[base + tid] : make_float4(0.f,0.f,0.f,0.f);
            r1 = (tid + 640 < nf4) ? ((const float4*)A2)[base + tid + 640] : make_float4(0.f,0.f,0.f,0.f);
            if (c + 1 == 3 && tid == 0) rt = A2[15624];
        }
        int nk = (c < 3) ? 32 : 29;
        const float* wbuf = sW + (c & 1) * 4000;
        if (j < 125) {
            const float* arow = &bufA[(c * 32) * NB + g * 4];
            for (int k = 0; k < nk; ++k) {
                float w = wbuf[k * 125 + j];
                float4 a = *(const float4*)&arow[k * NB];
                acc[0] += a.x * w; acc[1] += a.y * w; acc[2] += a.z * w; acc[3] += a.w * w;
            }
        }
        if (c < 3) {
            float* dst = sW + ((c + 1) & 1) * 4000;
            int nf4 = (c + 1 < 3) ? 1000 : 906;
            if (tid < nf4) ((float4*)dst)[tid] = r0;
            if (tid + 640 < nf4) ((float4*)dst)[tid + 640] = r1;
            if (c + 1 == 3 && tid == 0) dst[3624] = rt;
            __syncthreads();
        }
    }
    if (j < 125) {
        #pragma unroll
        for (int n = 0; n < 4; ++n) bufB[j * NB + g * 4 + n] = lrelu(acc[n]);
    }
    __syncthreads();
    // stage A3 (750 floats -> sW[0..750)) and B1 (4750 floats -> sW[752..5502))
    if (tid < 187) ((float4*)sW)[tid] = ((const float4*)A3)[tid];
    if (tid == 187) { sW[748] = A3[748]; sW[749] = A3[749]; }
    for (int t = tid; t < 1187; t += 640) ((float4*)(sW + 752))[t] = ((const float4*)B1)[t];
    if (tid == 188) { sW[752 + 4748] = B1[4748]; sW[752 + 4749] = B1[4749]; }
    __syncthreads();

    // ---- nn2 L3: 125 -> 6, 4-way k-split ----
    if (j < 24) {
        int jj = j % 6, s = j / 6;
        int k0 = s * 32, nk = (s < 3) ? 32 : 29;
        float ps[4] = {0.f, 0.f, 0.f, 0.f};
        for (int k = 0; k < nk; ++k) {
            float w = sW[(k0 + k) * 6 + jj];
            float4 a = *(const float4*)&bufB[(k0 + k) * NB + g * 4];
            ps[0] += a.x * w; ps[1] += a.y * w; ps[2] += a.z * w; ps[3] += a.w * w;
        }
        #pragma unroll
        for (int n = 0; n < 4; ++n) bufA[(s * 6 + jj) * NB + g * 4 + n] = ps[n];
    }
    __syncthreads();
    if (tid < 120) {
        int jj = tid / 20, n = tid % 20;
        float v = bufA[jj * NB + n] + bufA[(6 + jj) * NB + n]
                + bufA[(12 + jj) * NB + n] + bufA[(18 + jj) * NB + n] + ab3[jj];
        out_ids[(n0 + n) * 6 + jj] = v;
        bufC[(32 + jj) * NB + n] = v;
    }
    __syncthreads();

    // ---- nn3 L1: 38 -> 125 (B1 at sW+752) ----
    if (j < 125) {
        float bj = bb1[j];
        acc[0] = bj; acc[1] = bj; acc[2] = bj; acc[3] = bj;
        #pragma unroll 2
        for (int k = 0; k < 38; ++k) {
            float w = sW[752 + k * 125 + j];
            float4 a = *(const float4*)&bufC[k * NB + g * 4];
            acc[0] += a.x * w; acc[1] += a.y * w; acc[2] += a.z * w; acc[3] += a.w * w;
        }
        #pragma unroll
        for (int n = 0; n < 4; ++n) bufA[j * NB + g * 4 + n] = lrelu(acc[n]);
    }
    // prefetch B2 chunk0
    r0 = (tid < 1000) ? ((const float4*)B2)[tid] : make_float4(0.f,0.f,0.f,0.f);
    r1 = (tid < 360)  ? ((const float4*)B2)[tid + 640] : make_float4(0.f,0.f,0.f,0.f);
    __syncthreads();
    if (tid < 1000) ((float4*)sW)[tid] = r0;
    if (tid < 360)  ((float4*)sW)[tid + 640] = r1;
    __syncthreads();

    // ---- nn3 L2: 125 -> 125, chunked dbuf ----
    if (j < 125) { float bj = bb2[j]; acc[0] = bj; acc[1] = bj; acc[2] = bj; acc[3] = bj; }
    for (int c = 0; c < 4; ++c) {
        if (c < 3) {
            int base = (c + 1) * 1000, nf4 = (c + 1 < 3) ? 1000 : 906;
            r0 = (tid < nf4) ? ((const float4*)B2)[base + tid] : make_float4(0.f,0.f,0.f,0.f);
            r1 = (tid + 640 < nf4) ? ((const float4*)B2)[base + tid + 640] : make_float4(0.f,0.f,0.f,0.f);
            if (c + 1 == 3 && tid == 0) rt = B2[15624];
        }
        int nk = (c < 3) ? 32 : 29;
        const float* wbuf = sW + (c & 1) * 4000;
        if (j < 125) {
            const float* arow = &bufA[(c * 32) * NB + g * 4];
            for (int k = 0; k < nk; ++k) {
                float w = wbuf[k * 125 + j];
                float4 a = *(const float4*)&arow[k * NB];
                acc[0] += a.x * w; acc[1] += a.y * w; acc[2] += a.z * w; acc[3] += a.w * w;
            }
        }
        if (c < 3) {
            float* dst = sW + ((c + 1) & 1) * 4000;
            int nf4 = (c + 1 < 3) ? 1000 : 906;
            if (tid < nf4) ((float4*)dst)[tid] = r0;
            if (tid + 640 < nf4) ((float4*)dst)[tid + 640] = r1;
            if (c + 1 == 3 && tid == 0) dst[3624] = rt;
            __syncthreads();
        }
    }
    if (j < 125) {
        #pragma unroll
        for (int n = 0; n < 4; ++n) bufB[j * NB + g * 4 + n] = lrelu(acc[n]);
    }
    __syncthreads();
    // stage B3 (750 -> buf0; chunk3 used buf1)
    if (tid < 187) ((float4*)sW)[tid] = ((const float4*)B3)[tid];
    if (tid == 187) { sW[748] = B3[748]; sW[749] = B3[749]; }
    __syncthreads();

    // ---- nn3 L3: 125 -> 6, 4-way k-split ----
    if (j < 24) {
        int jj = j % 6, s = j / 6;
        int k0 = s * 32, nk = (s < 3) ? 32 : 29;
        float ps[4] = {0.f, 0.f, 0.f, 0.f};
        for (int k = 0; k < nk; ++k) {
            float w = sW[(k0 + k) * 6 + jj];
            float4 a = *(const float4*)&bufB[(k0 + k) * NB + g * 4];
            ps[0] += a.x * w; ps[1] += a.y * w; ps[2] += a.z * w; ps[3] += a.w * w;
        }
        #pragma unroll
        for (int n = 0; n < 4; ++n) bufA[(s * 6 + jj) * NB + g * 4 + n] = ps[n];
    }
    __syncthreads();
    if (tid < 120) {
        int jj = tid / 20, n = tid % 20;
        float v = bufA[jj * NB + n] + bufA[(6 + jj) * NB + n]
                + bufA[(12 + jj) * NB + n] + bufA[(18 + jj) * NB + n] + bb3[jj];
        out_p4[(n0 + n) * 6 + jj] = v;
    }
}

static inline int cdiv(int a, int b) { return (a + b - 1) / b; }

extern "C" void kernel_launch(void* const* d_in, const int* in_sizes, int n_in,
                              void* d_out, int out_size, void* d_ws, size_t ws_size,
                              hipStream_t stream) {
    const float* x        = (const float*)d_in[0];
    const float* ygen_id  = (const float*)d_in[1];
    const float* ygen     = (const float*)d_in[2];
    const float* codebook = (const float*)d_in[3];
    const float* nn1_W1 = (const float*)d_in[4];  const float* nn1_b1 = (const float*)d_in[5];
    const float* nn1_W2 = (const float*)d_in[6];  const float* nn1_b2 = (const float*)d_in[7];
    const float* nn1_W3 = (const float*)d_in[8];  const float* nn1_b3 = (const float*)d_in[9];
    const float* gcn_W  = (const float*)d_in[10]; const float* gcn_b  = (const float*)d_in[11];
    const float* gc_Wrel = (const float*)d_in[12]; const float* gc_brel = (const float*)d_in[13];
    const float* gc_Wroot = (const float*)d_in[14];
    const float* nn2_W1 = (const float*)d_in[15]; const float* nn2_b1 = (const float*)d_in[16];
    const float* nn2_W2 = (const float*)d_in[17]; const float* nn2_b2 = (const float*)d_in[18];
    const float* nn2_W3 = (const float*)d_in[19]; const float* nn2_b3 = (const float*)d_in[20];
    const float* nn3_W1 = (const float*)d_in[21]; const float* nn3_b1 = (const float*)d_in[22];
    const float* nn3_W2 = (const float*)d_in[23]; const float* nn3_b2 = (const float*)d_in[24];
    const float* nn3_W3 = (const float*)d_in[25]; const float* nn3_b3 = (const float*)d_in[26];

    float* out = (float*)d_out;
    float* ws  = (float*)d_ws;

    float* h      = ws + 0;         // 60000
    float* gcn_n  = ws + 60000;     // 160000
    float* agg_n  = ws + 220000;    // 160000
    float* dis_g  = ws + 380000;    // 5000
    _Float16* Mg  = (_Float16*)(ws + 385000);   // 520000 halves
    int* bin_idx  = (int*)(ws + 645000);        // 5000
    int* order    = (int*)(ws + 650000);        // 5000

    nn1_kernel<<<NN / NB, 640, 0, stream>>>(
        x, nn1_W1, nn1_b1, nn1_W2, nn1_b2, nn1_W3, nn1_b3, codebook,
        h, bin_idx);

    scatter_kernel<<<NBINS, 64, 0, stream>>>(
        bin_idx, order, (const float4*)ygen_id, (const float4*)ygen, (float4*)out);

    build_kernel<<<NBINS, 256, 0, stream>>>(h, order, Mg, dis_g);

    conv_kernel<<<NBINS * 4, 128, 0, stream>>>(
        Mg, dis_g, h, order, gcn_W, gcn_b, gcn_n, agg_n);

    nn23_kernel<<<NN / NB, 640, 0, stream>>>(
        gcn_n, agg_n, gc_Wrel, gc_brel, gc_Wroot,
        nn2_W1, nn2_b1, nn2_W2, nn2_b2, nn2_W3, nn2_b3,
        nn3_W1, nn3_b1, nn3_W2, nn3_b2, nn3_W3, nn3_b3,
        out, out + 30000);
}

// Round 9
// 196.645 us; speedup vs baseline: 4.3920x; 1.0962x over previous
//
#include <hip/hip_runtime.h>
#include <math.h>

#define NN 5000
#define NBINS 50
#define BINSZ 100
#define KNN 16
#define BPAD 104          // padded M row length (halves); 208 B stride, 16B aligned
#define MROWS 112         // padded row count in conv kernel
#define NB 20             // nodes per block in MLP kernels (5 groups x 4)

typedef _Float16 half8 __attribute__((ext_vector_type(8)));

__device__ __forceinline__ float lrelu(float x){ return x >= 0.f ? x : 0.01f*x; }

// =================== fused MLP1 + LSH bin: 250 blocks x 640 thr, 20 nodes/block =====
__global__ __launch_bounds__(640) void nn1_kernel(
    const float* __restrict__ x,
    const float* __restrict__ W1, const float* __restrict__ b1,
    const float* __restrict__ W2, const float* __restrict__ b2,
    const float* __restrict__ W3, const float* __restrict__ b3,
    const float* __restrict__ cb,
    float* __restrict__ h_out, int* __restrict__ bin_idx) {
    __shared__ float sW[8000];        // 2 x 4000 (32x125) chunk buffers
    __shared__ float bufX[12 * NB];
    __shared__ float bufA[125 * NB];
    __shared__ float bufB[125 * NB];
    __shared__ float sCB[300];
    int tid = threadIdx.x;
    int n0 = blockIdx.x * NB;         // 250 * 20 = 5000
    int g = tid >> 7, j = tid & 127;  // 5 groups x 128 (125 active)
    float acc[4];
    float4 r0, r1; float rt = 0.f;

    // ---- stage x (transposed [k][n]), codebook, W1 ----
    if (tid < 60) {
        float4 v = ((const float4*)(x + n0 * 12))[tid];
        int e = tid * 4;
        bufX[(e % 12) * NB + (e / 12)] = v.x;
        bufX[((e + 1) % 12) * NB + ((e + 1) / 12)] = v.y;
        bufX[((e + 2) % 12) * NB + ((e + 2) / 12)] = v.z;
        bufX[((e + 3) % 12) * NB + ((e + 3) / 12)] = v.w;
    }
    if (tid < 300) { int k = tid / 25, c = tid - k * 25; sCB[tid] = cb[k * 100 + c]; }
    if (tid < 375) ((float4*)sW)[tid] = ((const float4*)W1)[tid];   // 1500 floats
    __syncthreads();

    // ---- L1: 12 -> 125, leaky -> bufA[k][20] ----
    if (j < 125) {
        float bj = b1[j];
        acc[0] = bj; acc[1] = bj; acc[2] = bj; acc[3] = bj;
        #pragma unroll
        for (int k = 0; k < 12; ++k) {
            float w = sW[k * 125 + j];
            float4 a = *(const float4*)&bufX[k * NB + g * 4];
            acc[0] += a.x * w; acc[1] += a.y * w; acc[2] += a.z * w; acc[3] += a.w * w;
        }
        #pragma unroll
        for (int n = 0; n < 4; ++n) bufA[j * NB + g * 4 + n] = lrelu(acc[n]);
    }
    // prefetch W2 chunk0 (1000 float4: [tid] + [tid+640] halves)
    r0 = (tid < 1000) ? ((const float4*)W2)[tid] : make_float4(0.f,0.f,0.f,0.f);
    r1 = (tid < 360)  ? ((const float4*)W2)[tid + 640] : make_float4(0.f,0.f,0.f,0.f);
    __syncthreads();
    if (tid < 1000) ((float4*)sW)[tid] = r0;
    if (tid < 360)  ((float4*)sW)[tid + 640] = r1;
    __syncthreads();

    // ---- L2: 125 -> 125, chunked (32/32/32/29 rows), reg-prefetch dbuf ----
    if (j < 125) { float bj = b2[j]; acc[0] = bj; acc[1] = bj; acc[2] = bj; acc[3] = bj; }
    for (int c = 0; c < 4; ++c) {
        if (c < 3) {
            int base = (c + 1) * 1000, nf4 = (c + 1 < 3) ? 1000 : 906;
            r0 = (tid < nf4) ? ((const float4*)W2)[base + tid] : make_float4(0.f,0.f,0.f,0.f);
            r1 = (tid + 640 < nf4) ? ((const float4*)W2)[base + tid + 640] : make_float4(0.f,0.f,0.f,0.f);
            if (c + 1 == 3 && tid == 0) rt = W2[15624];
        }
        int nk = (c < 3) ? 32 : 29;
        const float* wbuf = sW + (c & 1) * 4000;
        if (j < 125) {
            const float* arow = &bufA[(c * 32) * NB + g * 4];
            for (int k = 0; k < nk; ++k) {
                float w = wbuf[k * 125 + j];
                float4 a = *(const float4*)&arow[k * NB];
                acc[0] += a.x * w; acc[1] += a.y * w; acc[2] += a.z * w; acc[3] += a.w * w;
            }
        }
        if (c < 3) {
            float* dst = sW + ((c + 1) & 1) * 4000;
            int nf4 = (c + 1 < 3) ? 1000 : 906;
            if (tid < nf4) ((float4*)dst)[tid] = r0;
            if (tid + 640 < nf4) ((float4*)dst)[tid + 640] = r1;
            if (c + 1 == 3 && tid == 0) dst[3624] = rt;
            __syncthreads();
        }
    }
    if (j < 125) {
        #pragma unroll
        for (int n = 0; n < 4; ++n) bufB[j * NB + g * 4 + n] = lrelu(acc[n]);
    }
    // stage W3 (375 float4 -> buf0; chunk3 compute used buf1, disjoint)
    __syncthreads();
    if (tid < 375) ((float4*)sW)[tid] = ((const float4*)W3)[tid];
    __syncthreads();

    // ---- L3: 125 -> 12, 4-way k-split (32/32/32/29) ----
    if (j < 48) {
        int jj = j % 12, s = j / 12;
        int k0 = s * 32, nk = (s < 3) ? 32 : 29;
        float ps[4] = {0.f, 0.f, 0.f, 0.f};
        for (int k = 0; k < nk; ++k) {
            float w = sW[(k0 + k) * 12 + jj];
            float4 a = *(const float4*)&bufB[(k0 + k) * NB + g * 4];
            ps[0] += a.x * w; ps[1] += a.y * w; ps[2] += a.z * w; ps[3] += a.w * w;
        }
        #pragma unroll
        for (int n = 0; n < 4; ++n) bufA[(s * 12 + jj) * NB + g * 4 + n] = ps[n];
    }
    __syncthreads();
    if (tid < 240) {
        int jj = tid / 20, n = tid % 20;
        float v = bufA[jj * NB + n] + bufA[(12 + jj) * NB + n]
                + bufA[(24 + jj) * NB + n] + bufA[(36 + jj) * NB + n] + b3[jj];
        h_out[(n0 + n) * 12 + jj] = v;
        bufB[jj * NB + n] = v;
    }
    __syncthreads();

    // ---- LSH bin (argmax over [mul,-mul], first max wins) ----
    if (tid < NB) {
        int n = tid;
        float hv[12];
        #pragma unroll
        for (int k = 0; k < 12; ++k) hv[k] = bufB[k * NB + n];
        float best = -INFINITY; int bi = 0;
        for (int c = 0; c < 25; ++c) {
            float m = 0.f;
            #pragma unroll
            for (int k = 0; k < 12; ++k) m += hv[k] * sCB[k * 25 + c];
            if (m > best) { best = m; bi = c; }
        }
        for (int c = 0; c < 25; ++c) {
            float m = 0.f;
            #pragma unroll
            for (int k = 0; k < 12; ++k) m += hv[k] * sCB[k * 25 + c];
            if (-m > best) { best = -m; bi = c + 25; }
        }
        bin_idx[n0 + n] = bi;
    }
}

// =================== stable argsort-by-bin (LDS-staged) =============================
__global__ __launch_bounds__(64) void scatter_kernel(
    const int* __restrict__ bin_idx, int* __restrict__ order) {
    __shared__ int sBI[NN];
    int b = blockIdx.x, lane = threadIdx.x;
    for (int t = lane; t < NN / 4; t += 64) ((int4*)sBI)[t] = ((const int4*)bin_idx)[t];
    __syncthreads();
    unsigned long long below = (lane == 0) ? 0ULL : ((~0ULL) >> (64 - lane));
    int cnt_lt = 0;
    for (int base = 0; base < NN; base += 64) {
        int i = base + lane;
        int bi = (i < NN) ? sBI[i] : 999;
        cnt_lt += __popcll(__ballot(bi < b));
    }
    int offs = cnt_lt;
    for (int base = 0; base < NN; base += 64) {
        int i = base + lane;
        int bi = (i < NN) ? sBI[i] : 999;
        unsigned long long m = __ballot(bi == b);
        if (bi == b) order[offs + __popcll(m & below)] = i;
        offs += __popcll(m);
    }
}

// =================== K1: build dense fp16 edge matrix M + dis (50 blocks) ===========
// Packed-key top-16: key = (sigmoid_bits & ~0x7F) | (127 - j)  -> tie-break embedded.
__global__ __launch_bounds__(256) void build_kernel(
    const float* __restrict__ h, const int* __restrict__ order,
    _Float16* __restrict__ Mg, float* __restrict__ dis_g) {
    __shared__ _Float16 M[BINSZ * BPAD];
    __shared__ float s_h[BINSZ * 12];
    __shared__ int   s_nodes[BINSZ];
    __shared__ unsigned s_tv[200 * KNN];     // 12.8 KB packed keys
    int p = blockIdx.x, tid = threadIdx.x;

    if (tid < BINSZ) s_nodes[tid] = order[p * BINSZ + tid];
    for (int t = tid; t < BINSZ * BPAD / 2; t += 256) ((int*)M)[t] = 0;
    __syncthreads();
    for (int t = tid; t < BINSZ * 12; t += 256) {
        int i = t / 12, k = t - i * 12;
        s_h[t] = h[s_nodes[i] * 12 + k];
    }
    __syncthreads();

    // local top-16 over 50 candidates (row = tid>>1, half = tid&1), packed keys
    if (tid < 200) {
        int row = tid >> 1, half = tid & 1;
        const float4* xp = (const float4*)&s_h[row * 12];
        float4 x0 = xp[0], x1 = xp[1], x2 = xp[2];
        unsigned tv[KNN];
        #pragma unroll
        for (int k = 0; k < KNN; ++k) tv[k] = 0u;
        int j0 = half * 50;
        for (int jj = 0; jj < 50; ++jj) {
            int j = j0 + jj;
            const float4* ap = (const float4*)&s_h[j * 12];
            float4 a0 = ap[0], a1 = ap[1], a2 = ap[2];
            float d = x0.x*a0.x + x0.y*a0.y + x0.z*a0.z + x0.w*a0.w
                    + x1.x*a1.x + x1.y*a1.y + x1.z*a1.z + x1.w*a1.w
                    + x2.x*a2.x + x2.y*a2.y + x2.z*a2.z + x2.w*a2.w;
            float v = 1.f / (1.f + expf(-d));
            unsigned key = (__float_as_uint(v) & 0xFFFFFF80u) | (unsigned)(127 - j);
            if (key > tv[KNN - 1]) {
                unsigned ins = key;
                #pragma unroll
                for (int k = 0; k < KNN; ++k) {
                    bool gt = ins > tv[k];
                    unsigned mx = gt ? ins : tv[k];
                    unsigned mn = gt ? tv[k] : ins;
                    tv[k] = mx; ins = mn;
                }
            }
        }
        #pragma unroll
        for (int k = 0; k < KNN; ++k) s_tv[tid * KNN + k] = tv[k];
    }
    __syncthreads();

    // merge two sorted 16-lists (keys embed tie-break; equality impossible)
    if (tid < BINSZ) {
        int base = tid * 32;
        int ia = 0, ib = 0;
        #pragma unroll
        for (int k = 0; k < KNN; ++k) {
            unsigned av = s_tv[base + ia], bv = s_tv[base + 16 + ib];
            bool tA = av > bv;
            unsigned key = tA ? av : bv;
            ia += tA; ib += !tA;
            int ix = 127 - (int)(key & 127u);
            float v = __uint_as_float(key & 0xFFFFFF80u);
            M[ix * BPAD + tid] = (_Float16)v;    // edge tid -> ix
        }
    }
    __syncthreads();

    for (int t = tid; t < BINSZ * BPAD / 8; t += 256)
        ((uint4*)(Mg + (size_t)p * BINSZ * BPAD))[t] = ((const uint4*)M)[t];
    if (tid < BINSZ) {
        float dsum = 1.0f;
        #pragma unroll 13
        for (int sc = 0; sc < 13; ++sc) {
            half8 m = *(const half8*)&M[tid * BPAD + sc * 8];
            dsum += (float)m[0] + (float)m[1] + (float)m[2] + (float)m[3]
                  + (float)m[4] + (float)m[5] + (float)m[6] + (float)m[7];
        }
        dis_g[p * BINSZ + tid] = 1.0f / sqrtf(dsum);
    }
}

// =================== K2: channel-sliced convs (200 blocks) + ygen passthrough =======
__global__ __launch_bounds__(128) void conv_kernel(
    const _Float16* __restrict__ Mg, const float* __restrict__ dis_g,
    const float* __restrict__ h, const int* __restrict__ order,
    const float* __restrict__ gcn_W, const float* __restrict__ gcn_b,
    float* __restrict__ gcn_n, float* __restrict__ agg_n,
    const float4* __restrict__ ygen_id4, const float4* __restrict__ ygen4,
    float4* __restrict__ out4) {
    __shared__ _Float16 M[MROWS * BPAD];
    __shared__ float s_h[BINSZ * 12];
    __shared__ int   s_nodes[BINSZ];
    __shared__ float s_dis[BINSZ];
    __shared__ float s_w[12 * 8];
    __shared__ float s_hWd[8 * BPAD];
    __shared__ float s_gcn[8 * BPAD];
    int bid = blockIdx.x, tid = threadIdx.x;
    int p = bid >> 2, cg = bid & 3, c0 = cg * 8;

    // passthrough: 200 blocks x 75 float4 = 15000 exactly
    if (tid < 75) {
        int gI = bid * 75 + tid;
        out4[15000 + gI] = (gI < 7500) ? ygen_id4[gI] : ygen4[gI - 7500];
    }
    if (tid < BINSZ) {
        s_nodes[tid] = order[p * BINSZ + tid];
        s_dis[tid]   = dis_g[p * BINSZ + tid];
    }
    for (int t = tid; t < 96; t += 128)
        s_w[t] = gcn_W[(t >> 3) * 32 + c0 + (t & 7)];
    for (int t = tid; t < BINSZ * BPAD / 8; t += 128)
        ((uint4*)M)[t] = ((const uint4*)(Mg + (size_t)p * BINSZ * BPAD))[t];
    for (int t = tid; t < (MROWS - BINSZ) * BPAD / 2; t += 128)
        ((int*)(M + BINSZ * BPAD))[t] = 0;
    if (tid < 32) {
        s_hWd[(tid >> 2) * BPAD + 100 + (tid & 3)] = 0.f;
        s_gcn[(tid >> 2) * BPAD + 100 + (tid & 3)] = 0.f;
    }
    __syncthreads();
    for (int t = tid; t < BINSZ * 12; t += 128) {
        int i = t / 12, k = t - i * 12;
        s_h[t] = h[s_nodes[i] * 12 + k];
    }
    __syncthreads();

    for (int o = tid; o < BINSZ * 8; o += 128) {
        int s = o >> 3, cc = o & 7;
        float a = 0.f;
        #pragma unroll
        for (int k = 0; k < 12; ++k) a += lrelu(s_h[s * 12 + k]) * s_w[k * 8 + cc];
        s_hWd[cc * BPAD + s] = s_dis[s] * a;
    }
    __syncthreads();

    int cc = tid & 7, dg = tid >> 3;
    {
        float acc[7];
        #pragma unroll
        for (int r = 0; r < 7; ++r) acc[r] = 0.f;
        for (int sc = 0; sc < 13; ++sc) {
            float4 hv0 = *(const float4*)&s_hWd[cc * BPAD + sc * 8];
            float4 hv1 = *(const float4*)&s_hWd[cc * BPAD + sc * 8 + 4];
            #pragma unroll
            for (int r = 0; r < 7; ++r) {
                int d = dg + 16 * r;
                half8 m = *(const half8*)&M[d * BPAD + sc * 8];
                acc[r] += (float)m[0]*hv0.x + (float)m[1]*hv0.y + (float)m[2]*hv0.z + (float)m[3]*hv0.w
                        + (float)m[4]*hv1.x + (float)m[5]*hv1.y + (float)m[6]*hv1.z + (float)m[7]*hv1.w;
            }
        }
        float bc = gcn_b[c0 + cc];
        #pragma unroll
        for (int r = 0; r < 7; ++r) {
            int d = dg + 16 * r;
            if (d < BINSZ) {
                float gq = s_dis[d] * (acc[r] + s_hWd[cc * BPAD + d]) + bc;
                s_gcn[cc * BPAD + d] = gq;
                gcn_n[s_nodes[d] * 32 + c0 + cc] = gq;
            }
        }
    }
    __syncthreads();
    {
        float acc[7];
        #pragma unroll
        for (int r = 0; r < 7; ++r) acc[r] = 0.f;
        for (int sc = 0; sc < 13; ++sc) {
            float4 hv0 = *(const float4*)&s_gcn[cc * BPAD + sc * 8];
            float4 hv1 = *(const float4*)&s_gcn[cc * BPAD + sc * 8 + 4];
            #pragma unroll
            for (int r = 0; r < 7; ++r) {
                int d = dg + 16 * r;
                half8 m = *(const half8*)&M[d * BPAD + sc * 8];
                acc[r] += (float)m[0]*hv0.x + (float)m[1]*hv0.y + (float)m[2]*hv0.z + (float)m[3]*hv0.w
                        + (float)m[4]*hv1.x + (float)m[5]*hv1.y + (float)m[6]*hv1.z + (float)m[7]*hv1.w;
            }
        }
        #pragma unroll
        for (int r = 0; r < 7; ++r) {
            int d = dg + 16 * r;
            if (d < BINSZ) agg_n[s_nodes[d] * 32 + c0 + cc] = acc[r];
        }
    }
}

// =================== fused combine + nn2 + nn3: 250 blocks x 640 thr ================
__global__ __launch_bounds__(640) void nn23_kernel(
    const float* __restrict__ gcn_n, const float* __restrict__ agg_n,
    const float* __restrict__ Wrel, const float* __restrict__ brel,
    const float* __restrict__ Wroot,
    const float* __restrict__ A1, const float* __restrict__ ab1,
    const float* __restrict__ A2, const float* __restrict__ ab2,
    const float* __restrict__ A3, const float* __restrict__ ab3,
    const float* __restrict__ B1, const float* __restrict__ bb1,
    const float* __restrict__ B2, const float* __restrict__ bb2,
    const float* __restrict__ B3, const float* __restrict__ bb3,
    float* __restrict__ out_ids, float* __restrict__ out_p4) {
    __shared__ float sW[8000];          // layout phase1: Wrel[0..1024) Wroot[1024..2048) A1[2048..6048)
    __shared__ float sAG[32 * NB];      // [k][n]
    __shared__ float sGC[32 * NB];
    __shared__ float bufC[38 * NB];     // combine out rows 0..31, ids rows 32..37
    __shared__ float bufA[125 * NB];
    __shared__ float bufB[125 * NB];
    int tid = threadIdx.x;
    int n0 = blockIdx.x * NB;
    int g = tid >> 7, j = tid & 127;
    float acc[4];
    float4 r0, r1; float rt = 0.f;

    // ---- stage agg/gcn transposed + Wrel/Wroot + A1 (all concurrent, one sync) ----
    if (tid < 160) {
        float4 va = ((const float4*)(agg_n + n0 * 32))[tid];
        float4 vg = ((const float4*)(gcn_n + n0 * 32))[tid];
        int e = tid * 4, n = e / 32, k = e % 32;
        sAG[k * NB + n] = va.x; sAG[(k+1) * NB + n] = va.y;
        sAG[(k+2) * NB + n] = va.z; sAG[(k+3) * NB + n] = va.w;
        sGC[k * NB + n] = vg.x; sGC[(k+1) * NB + n] = vg.y;
        sGC[(k+2) * NB + n] = vg.z; sGC[(k+3) * NB + n] = vg.w;
    }
    if (tid >= 160 && tid < 416) ((float4*)sW)[tid - 160] = ((const float4*)Wrel)[tid - 160];
    if (tid >= 416 && tid < 640) ((float4*)(sW + 1024))[tid - 416] = ((const float4*)Wroot)[tid - 416];
    if (tid < 32) ((float4*)(sW + 1024))[224 + tid] = ((const float4*)Wroot)[224 + tid];
    for (int t = tid; t < 1000; t += 640) ((float4*)(sW + 2048))[t] = ((const float4*)A1)[t];
    __syncthreads();

    // ---- combine: bufC[jc][n] = leaky(agg@Wrel + brel + gcn@Wroot), 32x20=640 thr ---
    {
        int jc = tid / 20, n = tid % 20;
        float a = brel[jc];
        #pragma unroll 8
        for (int k = 0; k < 32; ++k)
            a += sAG[k * NB + n] * sW[k * 32 + jc] + sGC[k * NB + n] * sW[1024 + k * 32 + jc];
        bufC[jc * NB + n] = lrelu(a);
    }
    __syncthreads();

    // ---- nn2 L1: 32 -> 125 (A1 at sW+2048) ----
    if (j < 125) {
        float bj = ab1[j];
        acc[0] = bj; acc[1] = bj; acc[2] = bj; acc[3] = bj;
        #pragma unroll 8
        for (int k = 0; k < 32; ++k) {
            float w = sW[2048 + k * 125 + j];
            float4 a = *(const float4*)&bufC[k * NB + g * 4];
            acc[0] += a.x * w; acc[1] += a.y * w; acc[2] += a.z * w; acc[3] += a.w * w;
        }
        #pragma unroll
        for (int n = 0; n < 4; ++n) bufA[j * NB + g * 4 + n] = lrelu(acc[n]);
    }
    // prefetch A2 chunk0
    r0 = (tid < 1000) ? ((const float4*)A2)[tid] : make_float4(0.f,0.f,0.f,0.f);
    r1 = (tid < 360)  ? ((const float4*)A2)[tid + 640] : make_float4(0.f,0.f,0.f,0.f);
    __syncthreads();
    if (tid < 1000) ((float4*)sW)[tid] = r0;
    if (tid < 360)  ((float4*)sW)[tid + 640] = r1;
    __syncthreads();

    // ---- nn2 L2: 125 -> 125, chunked dbuf ----
    if (j < 125) { float bj = ab2[j]; acc[0] = bj; acc[1] = bj; acc[2] = bj; acc[3] = bj; }
    for (int c = 0; c < 4; ++c) {
        if (c < 3) {
            int base = (c + 1) * 1000, nf4 = (c + 1 < 3) ? 1000 : 906;
            r0 = (tid < nf4) ? ((const float4*)A2)[base + tid] : make_float4(0.f,0.f,0.f,0.f);
            r1 = (tid + 640 < nf4) ? ((const float4*)A2)[base + tid + 640] : make_float4(0.f,0.f,0.f,0.f);
            if (c + 1 == 3 && tid == 0) rt = A2[15624];
        }
        int nk = (c < 3) ? 32 : 29;
        const float* wbuf = sW + (c & 1) * 4000;
        if (j < 125) {
            const float* arow = &bufA[(c * 32) * NB + g * 4];
            for (int k = 0; k < nk; ++k) {
                float w = wbuf[k * 125 + j];
                float4 a = *(const float4*)&arow[k * NB];
                acc[0] += a.x * w; acc[1] += a.y * w; acc[2] += a.z * w; acc[3] += a.w * w;
            }
        }
        if (c < 3) {
            float* dst = sW + ((c + 1) & 1) * 4000;
            int nf4 = (c + 1 < 3) ? 1000 : 906;
            if (tid < nf4) ((float4*)dst)[tid] = r0;
            if (tid + 640 < nf4) ((float4*)dst)[tid + 640] = r1;
            if (c + 1 == 3 && tid == 0) dst[3624] = rt;
            __syncthreads();
        }
    }
    if (j < 125) {
        #pragma unroll
        for (int n = 0; n < 4; ++n) bufB[j * NB + g * 4 + n] = lrelu(acc[n]);
    }
    __syncthreads();
    // stage A3 (750 floats -> sW[0..750)) and B1 (4750 floats -> sW[752..5502))
    if (tid < 187) ((float4*)sW)[tid] = ((const float4*)A3)[tid];
    if (tid == 187) { sW[748] = A3[748]; sW[749] = A3[749]; }
    for (int t = tid; t < 1187; t += 640) ((float4*)(sW + 752))[t] = ((const float4*)B1)[t];
    if (tid == 188) { sW[752 + 4748] = B1[4748]; sW[752 + 4749] = B1[4749]; }
    __syncthreads();

    // ---- nn2 L3: 125 -> 6, 4-way k-split ----
    if (j < 24) {
        int jj = j % 6, s = j / 6;
        int k0 = s * 32, nk = (s < 3) ? 32 : 29;
        float ps[4] = {0.f, 0.f, 0.f, 0.f};
        for (int k = 0; k < nk; ++k) {
            float w = sW[(k0 + k) * 6 + jj];
            float4 a = *(const float4*)&bufB[(k0 + k) * NB + g * 4];
            ps[0] += a.x * w; ps[1] += a.y * w; ps[2] += a.z * w; ps[3] += a.w * w;
        }
        #pragma unroll
        for (int n = 0; n < 4; ++n) bufA[(s * 6 + jj) * NB + g * 4 + n] = ps[n];
    }
    __syncthreads();
    if (tid < 120) {
        int jj = tid / 20, n = tid % 20;
        float v = bufA[jj * NB + n] + bufA[(6 + jj) * NB + n]
                + bufA[(12 + jj) * NB + n] + bufA[(18 + jj) * NB + n] + ab3[jj];
        out_ids[(n0 + n) * 6 + jj] = v;
        bufC[(32 + jj) * NB + n] = v;
    }
    __syncthreads();

    // ---- nn3 L1: 38 -> 125 (B1 at sW+752) ----
    if (j < 125) {
        float bj = bb1[j];
        acc[0] = bj; acc[1] = bj; acc[2] = bj; acc[3] = bj;
        #pragma unroll 2
        for (int k = 0; k < 38; ++k) {
            float w = sW[752 + k * 125 + j];
            float4 a = *(const float4*)&bufC[k * NB + g * 4];
            acc[0] += a.x * w; acc[1] += a.y * w; acc[2] += a.z * w; acc[3] += a.w * w;
        }
        #pragma unroll
        for (int n = 0; n < 4; ++n) bufA[j * NB + g * 4 + n] = lrelu(acc[n]);
    }
    // prefetch B2 chunk0
    r0 = (tid < 1000) ? ((const float4*)B2)[tid] : make_float4(0.f,0.f,0.f,0.f);
    r1 = (tid < 360)  ? ((const float4*)B2)[tid + 640] : make_float4(0.f,0.f,0.f,0.f);
    __syncthreads();
    if (tid < 1000) ((float4*)sW)[tid] = r0;
    if (tid < 360)  ((float4*)sW)[tid + 640] = r1;
    __syncthreads();

    // ---- nn3 L2: 125 -> 125, chunked dbuf ----
    if (j < 125) { float bj = bb2[j]; acc[0] = bj; acc[1] = bj; acc[2] = bj; acc[3] = bj; }
    for (int c = 0; c < 4; ++c) {
        if (c < 3) {
            int base = (c + 1) * 1000, nf4 = (c + 1 < 3) ? 1000 : 906;
            r0 = (tid < nf4) ? ((const float4*)B2)[base + tid] : make_float4(0.f,0.f,0.f,0.f);
            r1 = (tid + 640 < nf4) ? ((const float4*)B2)[base + tid + 640] : make_float4(0.f,0.f,0.f,0.f);
            if (c + 1 == 3 && tid == 0) rt = B2[15624];
        }
        int nk = (c < 3) ? 32 : 29;
        const float* wbuf = sW + (c & 1) * 4000;
        if (j < 125) {
            const float* arow = &bufA[(c * 32) * NB + g * 4];
            for (int k = 0; k < nk; ++k) {
                float w = wbuf[k * 125 + j];
                float4 a = *(const float4*)&arow[k * NB];
                acc[0] += a.x * w; acc[1] += a.y * w; acc[2] += a.z * w; acc[3] += a.w * w;
            }
        }
        if (c < 3) {
            float* dst = sW + ((c + 1) & 1) * 4000;
            int nf4 = (c + 1 < 3) ? 1000 : 906;
            if (tid < nf4) ((float4*)dst)[tid] = r0;
            if (tid + 640 < nf4) ((float4*)dst)[tid + 640] = r1;
            if (c + 1 == 3 && tid == 0) dst[3624] = rt;
            __syncthreads();
        }
    }
    if (j < 125) {
        #pragma unroll
        for (int n = 0; n < 4; ++n) bufB[j * NB + g * 4 + n] = lrelu(acc[n]);
    }
    __syncthreads();
    // stage B3 (750 -> buf0; chunk3 used buf1)
    if (tid < 187) ((float4*)sW)[tid] = ((const float4*)B3)[tid];
    if (tid == 187) { sW[748] = B3[748]; sW[749] = B3[749]; }
    __syncthreads();

    // ---- nn3 L3: 125 -> 6, 4-way k-split ----
    if (j < 24) {
        int jj = j % 6, s = j / 6;
        int k0 = s * 32, nk = (s < 3) ? 32 : 29;
        float ps[4] = {0.f, 0.f, 0.f, 0.f};
        for (int k = 0; k < nk; ++k) {
            float w = sW[(k0 + k) * 6 + jj];
            float4 a = *(const float4*)&bufB[(k0 + k) * NB + g * 4];
            ps[0] += a.x * w; ps[1] += a.y * w; ps[2] += a.z * w; ps[3] += a.w * w;
        }
        #pragma unroll
        for (int n = 0; n < 4; ++n) bufA[(s * 6 + jj) * NB + g * 4 + n] = ps[n];
    }
    __syncthreads();
    if (tid < 120) {
        int jj = tid / 20, n = tid % 20;
        float v = bufA[jj * NB + n] + bufA[(6 + jj) * NB + n]
                + bufA[(12 + jj) * NB + n] + bufA[(18 + jj) * NB + n] + bb3[jj];
        out_p4[(n0 + n) * 6 + jj] = v;
    }
}

static inline int cdiv(int a, int b) { return (a + b - 1) / b; }

extern "C" void kernel_launch(void* const* d_in, const int* in_sizes, int n_in,
                              void* d_out, int out_size, void* d_ws, size_t ws_size,
                              hipStream_t stream) {
    const float* x        = (const float*)d_in[0];
    const float* ygen_id  = (const float*)d_in[1];
    const float* ygen     = (const float*)d_in[2];
    const float* codebook = (const float*)d_in[3];
    const float* nn1_W1 = (const float*)d_in[4];  const float* nn1_b1 = (const float*)d_in[5];
    const float* nn1_W2 = (const float*)d_in[6];  const float* nn1_b2 = (const float*)d_in[7];
    const float* nn1_W3 = (const float*)d_in[8];  const float* nn1_b3 = (const float*)d_in[9];
    const float* gcn_W  = (const float*)d_in[10]; const float* gcn_b  = (const float*)d_in[11];
    const float* gc_Wrel = (const float*)d_in[12]; const float* gc_brel = (const float*)d_in[13];
    const float* gc_Wroot = (const float*)d_in[14];
    const float* nn2_W1 = (const float*)d_in[15]; const float* nn2_b1 = (const float*)d_in[16];
    const float* nn2_W2 = (const float*)d_in[17]; const float* nn2_b2 = (const float*)d_in[18];
    const float* nn2_W3 = (const float*)d_in[19]; const float* nn2_b3 = (const float*)d_in[20];
    const float* nn3_W1 = (const float*)d_in[21]; const float* nn3_b1 = (const float*)d_in[22];
    const float* nn3_W2 = (const float*)d_in[23]; const float* nn3_b2 = (const float*)d_in[24];
    const float* nn3_W3 = (const float*)d_in[25]; const float* nn3_b3 = (const float*)d_in[26];

    float* out = (float*)d_out;
    float* ws  = (float*)d_ws;

    float* h      = ws + 0;         // 60000
    float* gcn_n  = ws + 60000;     // 160000
    float* agg_n  = ws + 220000;    // 160000
    float* dis_g  = ws + 380000;    // 5000
    _Float16* Mg  = (_Float16*)(ws + 385000);   // 520000 halves
    int* bin_idx  = (int*)(ws + 645000);        // 5000
    int* order    = (int*)(ws + 650000);        // 5000

    nn1_kernel<<<NN / NB, 640, 0, stream>>>(
        x, nn1_W1, nn1_b1, nn1_W2, nn1_b2, nn1_W3, nn1_b3, codebook,
        h, bin_idx);

    scatter_kernel<<<NBINS, 64, 0, stream>>>(bin_idx, order);

    build_kernel<<<NBINS, 256, 0, stream>>>(h, order, Mg, dis_g);

    conv_kernel<<<NBINS * 4, 128, 0, stream>>>(
        Mg, dis_g, h, order, gcn_W, gcn_b, gcn_n, agg_n,
        (const float4*)ygen_id, (const float4*)ygen, (float4*)out);

    nn23_kernel<<<NN / NB, 640, 0, stream>>>(
        gcn_n, agg_n, gc_Wrel, gc_brel, gc_Wroot,
        nn2_W1, nn2_b1, nn2_W2, nn2_b2, nn2_W3, nn2_b3,
        nn3_W1, nn3_b1, nn3_W2, nn3_b2, nn3_W3, nn3_b3,
        out, out + 30000);
}